// Round 3
// baseline (508.041 us; speedup 1.0000x reference)
//
#include <hip/hip_runtime.h>

typedef __attribute__((ext_vector_type(8))) short  s16x8;
typedef __attribute__((ext_vector_type(8))) unsigned short u16x8;
typedef __attribute__((ext_vector_type(4))) float  f32x4;

constexpr float BN_EPS = 1e-5f;
#define DEV_INLINE __device__ __forceinline__

DEV_INLINE ushort f2bf(float f) {
  unsigned int u = __float_as_uint(f);
  return (ushort)((u + 0x7FFFu + ((u >> 16) & 1u)) >> 16);
}

DEV_INLINE f32x4 mfma16(s16x8 a, s16x8 b, f32x4 c) {
  return __builtin_amdgcn_mfma_f32_16x16x32_bf16(a, b, c, 0, 0, 0);
}

// packed B-fragment index decode: r in [0,1024) -> (k, col16)
DEV_INLINE void decode_frag(int r, int& k, int& c16) {
  const int ks = r >> 9;
  const int l = (r >> 3) & 63;
  const int j = r & 7;
  k = ks * 32 + ((l >> 4) << 3) + j;
  c16 = l & 15;
}

__global__ void kZero(float* p, int n) {
  int i = blockIdx.x * blockDim.x + threadIdx.x;
  if (i < n) p[i] = 0.f;
}

// ---- pack W1|Ws (20 ct), Wk (9 taps x 4 ct), W3 (16 ct) into B-fragment order
__global__ void kPackW(const float* __restrict__ W1, const float* __restrict__ Ws,
                       const float* __restrict__ Wk, const float* __restrict__ W3,
                       ushort* __restrict__ WP1S, ushort* __restrict__ WPk,
                       ushort* __restrict__ WP3) {
  int e = blockIdx.x * 256 + threadIdx.x;  // 73728 total
  if (e < 20480) {
    int ct = e >> 10, r = e & 1023, k, c16;
    decode_frag(r, k, c16);
    float w = (ct < 4) ? W1[k * 64 + ct * 16 + c16] : Ws[k * 256 + (ct - 4) * 16 + c16];
    WP1S[e] = f2bf(w);
  } else if (e < 57344) {
    int e2 = e - 20480;
    int tap = e2 >> 12, r2 = e2 & 4095;
    int ct = r2 >> 10, k, c16;
    decode_frag(r2 & 1023, k, c16);
    WPk[e2] = f2bf(Wk[tap * 4096 + k * 64 + ct * 16 + c16]);
  } else {
    int e3 = e - 57344;
    int ct = e3 >> 10, k, c16;
    decode_frag(e3 & 1023, k, c16);
    WP3[e3] = f2bf(W3[k * 256 + ct * 16 + c16]);
  }
}

// ---- finalize BN affine params from col sums -------------------------------
__global__ void kFinStats(const float* __restrict__ sum, const float* __restrict__ sq,
                          const float* __restrict__ g, const float* __restrict__ b,
                          float invN, float* __restrict__ a, float* __restrict__ c, int n) {
  int j = blockIdx.x * blockDim.x + threadIdx.x;
  if (j < n) {
    float m = sum[j] * invN;
    float v = fmaxf(sq[j] * invN - m * m, 0.f);
    float al = g[j] * rsqrtf(v + BN_EPS);
    a[j] = al;
    c[j] = fmaf(-m, al, b[j]);
  }
}

// ---- pack scaled W3*diag(a3), Ws*diag(aS); cc = c3+cS ----------------------
__global__ void kPackScaled(const float* __restrict__ W3, const float* __restrict__ Ws,
                            const float* __restrict__ a3v, const float* __restrict__ aSv,
                            const float* __restrict__ c3v, const float* __restrict__ cSv,
                            ushort* __restrict__ WP3s, ushort* __restrict__ WPSs,
                            float* __restrict__ cc) {
  int e = blockIdx.x * 256 + threadIdx.x;  // 16384
  int ct = e >> 10, k, c16;
  decode_frag(e & 1023, k, c16);
  int col = ct * 16 + c16;
  WP3s[e] = f2bf(W3[k * 256 + col] * a3v[col]);
  WPSs[e] = f2bf(Ws[k * 256 + col] * aSv[col]);
  if (e < 256) cc[e] = c3v[e] + cSv[e];
}

// ---- stage one 64-row f32 tile into swizzled bf16 LDS ----------------------
// thread t handles row r=t>>2, cols [q*16, q*16+16)
DEV_INLINE void stageF32(ushort* At, const float* __restrict__ src, int row0, int N,
                         int tid, float scale_dummy) {
  const int r = tid >> 2, q = tid & 3;
  const int grow = row0 + r;
  u16x8 lo = {0, 0, 0, 0, 0, 0, 0, 0}, hi = {0, 0, 0, 0, 0, 0, 0, 0};
  if (grow < N) {
    const float4* xp = reinterpret_cast<const float4*>(&src[(size_t)grow * 64 + q * 16]);
#pragma unroll
    for (int i = 0; i < 2; ++i) {
      float4 t = xp[i];
      lo[4 * i + 0] = f2bf(t.x); lo[4 * i + 1] = f2bf(t.y);
      lo[4 * i + 2] = f2bf(t.z); lo[4 * i + 3] = f2bf(t.w);
      float4 u = xp[i + 2];
      hi[4 * i + 0] = f2bf(u.x); hi[4 * i + 1] = f2bf(u.y);
      hi[4 * i + 2] = f2bf(u.z); hi[4 * i + 3] = f2bf(u.w);
    }
  }
  char* base = (char*)At + r * 128;
  const int sw = (r & 7) << 4;
  *(u16x8*)(base + ((q * 32) ^ sw)) = lo;
  *(u16x8*)(base + ((q * 32 + 16) ^ sw)) = hi;
}

// ---- K1: colsum/colsq of X@[W1|Ws] (320 cols), no Y store ------------------
__global__ __launch_bounds__(256) void kStatsXW(const float* __restrict__ X,
                                                const ushort* __restrict__ WP,
                                                float* __restrict__ gsum,
                                                float* __restrict__ gsq, int N) {
  __shared__ ushort At[64 * 64];
  __shared__ float lsum[320], lsq[320];
  const int tid = threadIdx.x;
  const int row0 = blockIdx.x * 64;
  for (int i = tid; i < 320; i += 256) { lsum[i] = 0.f; lsq[i] = 0.f; }
  stageF32(At, X, row0, N, tid, 0.f);
  __syncthreads();
  const int l = tid & 63, w = tid >> 6;
  const int rowb = w * 16 + (l & 15);
  const char* abase = (const char*)At + rowb * 128;
  const int sw = (rowb & 7) << 4;
  const int kb = (l >> 4) << 4;
  const s16x8 a0 = *(const s16x8*)(abase + (kb ^ sw));
  const s16x8 a1 = *(const s16x8*)(abase + ((64 + kb) ^ sw));
  const u16x8* wp = (const u16x8*)WP;
#pragma unroll 5
  for (int ct = 0; ct < 20; ++ct) {
    s16x8 b0 = (s16x8)wp[(ct * 2 + 0) * 64 + l];
    s16x8 b1 = (s16x8)wp[(ct * 2 + 1) * 64 + l];
    f32x4 acc = {0.f, 0.f, 0.f, 0.f};
    acc = mfma16(a0, b0, acc);
    acc = mfma16(a1, b1, acc);
    float sp = acc[0] + acc[1] + acc[2] + acc[3];
    float qp = acc[0] * acc[0] + acc[1] * acc[1] + acc[2] * acc[2] + acc[3] * acc[3];
    sp += __shfl_xor(sp, 16); sp += __shfl_xor(sp, 32);
    qp += __shfl_xor(qp, 16); qp += __shfl_xor(qp, 32);
    if ((l >> 4) == 0) {
      atomicAdd(&lsum[ct * 16 + (l & 15)], sp);
      atomicAdd(&lsq[ct * 16 + (l & 15)], qp);
    }
  }
  __syncthreads();
  for (int i = tid; i < 320; i += 256) {
    atomicAdd(&gsum[i], lsum[i]);
    atomicAdd(&gsq[i], lsq[i]);
  }
}

// ---- K2: h1 = relu(a1*(X@W1)+c1) -> bf16 -----------------------------------
__global__ __launch_bounds__(256) void kGemm1(const float* __restrict__ X,
                                              const ushort* __restrict__ WP,
                                              const float* __restrict__ av,
                                              const float* __restrict__ cv,
                                              ushort* __restrict__ H1, int N) {
  __shared__ ushort At[64 * 64];
  const int tid = threadIdx.x;
  const int row0 = blockIdx.x * 64;
  stageF32(At, X, row0, N, tid, 0.f);
  __syncthreads();
  const int l = tid & 63, w = tid >> 6;
  const int rowb = w * 16 + (l & 15);
  const char* abase = (const char*)At + rowb * 128;
  const int sw = (rowb & 7) << 4;
  const int kb = (l >> 4) << 4;
  const s16x8 a0 = *(const s16x8*)(abase + (kb ^ sw));
  const s16x8 a1 = *(const s16x8*)(abase + ((64 + kb) ^ sw));
  const u16x8* wp = (const u16x8*)WP;
#pragma unroll
  for (int ct = 0; ct < 4; ++ct) {
    s16x8 b0 = (s16x8)wp[(ct * 2 + 0) * 64 + l];
    s16x8 b1 = (s16x8)wp[(ct * 2 + 1) * 64 + l];
    f32x4 acc = {0.f, 0.f, 0.f, 0.f};
    acc = mfma16(a0, b0, acc);
    acc = mfma16(a1, b1, acc);
    const int col = ct * 16 + (l & 15);
    const float aj = av[col], cj = cv[col];
#pragma unroll
    for (int reg = 0; reg < 4; ++reg) {
      const int grow = row0 + w * 16 + ((l >> 4) << 2) + reg;
      if (grow < N) H1[(size_t)grow * 64 + col] = f2bf(fmaxf(fmaf(acc[reg], aj, cj), 0.f));
    }
  }
}

// ---- K3: Y2 = sum_k gather_k(h1) @ Wk[k] (MFMA) + BN2 col stats ------------
__global__ __launch_bounds__(256) void kConv(const ushort* __restrict__ H1,
                                             const int* __restrict__ nbr,
                                             const ushort* __restrict__ WPk,
                                             float* __restrict__ Y2,
                                             float* __restrict__ gsum,
                                             float* __restrict__ gsq, int N) {
  __shared__ ushort At[64 * 64];
  __shared__ int idx[576];
  __shared__ float lsum[64], lsq[64];
  const int tid = threadIdx.x;
  const int row0 = blockIdx.x * 64;
  if (tid < 64) { lsum[tid] = 0.f; lsq[tid] = 0.f; }
  for (int e = tid; e < 576; e += 256) {
    const int grow = row0 + e / 9;
    idx[e] = (grow < N) ? nbr[(size_t)row0 * 9 + e] : -1;
  }
  const int l = tid & 63, w = tid >> 6;
  const int rowb = w * 16 + (l & 15);
  const char* abase = (const char*)At + rowb * 128;
  const int swr = (rowb & 7) << 4;
  const int kb = (l >> 4) << 4;
  const int r = tid >> 2, q = tid & 3;
  char* wbase = (char*)At + r * 128;
  const int sww = (r & 7) << 4;
  f32x4 acc[4];
#pragma unroll
  for (int ct = 0; ct < 4; ++ct) acc[ct] = {0.f, 0.f, 0.f, 0.f};
  const u16x8* wp = (const u16x8*)WPk;
  for (int k = 0; k < 9; ++k) {
    __syncthreads();  // idx ready (k=0) / prev reads done
    const int src = idx[r * 9 + k];
    u16x8 lo = {0, 0, 0, 0, 0, 0, 0, 0}, hi = {0, 0, 0, 0, 0, 0, 0, 0};
    if (src >= 0) {
      const u16x8* hp = (const u16x8*)&H1[(size_t)src * 64 + q * 16];
      lo = hp[0];
      hi = hp[1];
    }
    *(u16x8*)(wbase + ((q * 32) ^ sww)) = lo;
    *(u16x8*)(wbase + ((q * 32 + 16) ^ sww)) = hi;
    __syncthreads();
    const s16x8 a0 = *(const s16x8*)(abase + (kb ^ swr));
    const s16x8 a1 = *(const s16x8*)(abase + ((64 + kb) ^ swr));
#pragma unroll
    for (int ct = 0; ct < 4; ++ct) {
      s16x8 b0 = (s16x8)wp[((size_t)((k * 4 + ct) * 2 + 0)) * 64 + l];
      s16x8 b1 = (s16x8)wp[((size_t)((k * 4 + ct) * 2 + 1)) * 64 + l];
      acc[ct] = mfma16(a0, b0, acc[ct]);
      acc[ct] = mfma16(a1, b1, acc[ct]);
    }
  }
#pragma unroll
  for (int ct = 0; ct < 4; ++ct) {
    const f32x4 v = acc[ct];
    const int col = ct * 16 + (l & 15);
#pragma unroll
    for (int reg = 0; reg < 4; ++reg) {
      const int grow = row0 + w * 16 + ((l >> 4) << 2) + reg;
      if (grow < N) Y2[(size_t)grow * 64 + col] = v[reg];
    }
    float sp = v[0] + v[1] + v[2] + v[3];
    float qp = v[0] * v[0] + v[1] * v[1] + v[2] * v[2] + v[3] * v[3];
    sp += __shfl_xor(sp, 16); sp += __shfl_xor(sp, 32);
    qp += __shfl_xor(qp, 16); qp += __shfl_xor(qp, 32);
    if ((l >> 4) == 0) {
      atomicAdd(&lsum[col], sp);
      atomicAdd(&lsq[col], qp);
    }
  }
  __syncthreads();
  if (tid < 64) {
    atomicAdd(&gsum[tid], lsum[tid]);
    atomicAdd(&gsq[tid], lsq[tid]);
  }
}

// ---- K4: h2 = relu(a2*Y2+c2) -> bf16 store + BN3 stats (h2@W3) -------------
__global__ __launch_bounds__(256) void kH2S3(const float* __restrict__ Y2,
                                             const float* __restrict__ a2v,
                                             const float* __restrict__ c2v,
                                             const ushort* __restrict__ WP3,
                                             ushort* __restrict__ H2,
                                             float* __restrict__ gsum,
                                             float* __restrict__ gsq, int N) {
  __shared__ ushort At[64 * 64];
  __shared__ float lsum[256], lsq[256];
  __shared__ float a2s[64], c2s[64];
  const int tid = threadIdx.x;
  const int row0 = blockIdx.x * 64;
  for (int i = tid; i < 256; i += 256) { lsum[i] = 0.f; lsq[i] = 0.f; }
  if (tid < 64) a2s[tid] = a2v[tid];
  else if (tid < 128) c2s[tid - 64] = c2v[tid - 64];
  __syncthreads();
  {
    const int r = tid >> 2, q = tid & 3;
    const int grow = row0 + r;
    u16x8 lo = {0, 0, 0, 0, 0, 0, 0, 0}, hi = {0, 0, 0, 0, 0, 0, 0, 0};
    if (grow < N) {
      const float4* yp = reinterpret_cast<const float4*>(&Y2[(size_t)grow * 64 + q * 16]);
#pragma unroll
      for (int i = 0; i < 2; ++i) {
        float4 t = yp[i];
        float4 u = yp[i + 2];
        const int cb = q * 16;
        lo[4 * i + 0] = f2bf(fmaxf(fmaf(t.x, a2s[cb + 4 * i + 0], c2s[cb + 4 * i + 0]), 0.f));
        lo[4 * i + 1] = f2bf(fmaxf(fmaf(t.y, a2s[cb + 4 * i + 1], c2s[cb + 4 * i + 1]), 0.f));
        lo[4 * i + 2] = f2bf(fmaxf(fmaf(t.z, a2s[cb + 4 * i + 2], c2s[cb + 4 * i + 2]), 0.f));
        lo[4 * i + 3] = f2bf(fmaxf(fmaf(t.w, a2s[cb + 4 * i + 3], c2s[cb + 4 * i + 3]), 0.f));
        hi[4 * i + 0] = f2bf(fmaxf(fmaf(u.x, a2s[cb + 8 + 4 * i + 0], c2s[cb + 8 + 4 * i + 0]), 0.f));
        hi[4 * i + 1] = f2bf(fmaxf(fmaf(u.y, a2s[cb + 8 + 4 * i + 1], c2s[cb + 8 + 4 * i + 1]), 0.f));
        hi[4 * i + 2] = f2bf(fmaxf(fmaf(u.z, a2s[cb + 8 + 4 * i + 2], c2s[cb + 8 + 4 * i + 2]), 0.f));
        hi[4 * i + 3] = f2bf(fmaxf(fmaf(u.w, a2s[cb + 8 + 4 * i + 3], c2s[cb + 8 + 4 * i + 3]), 0.f));
      }
      *(u16x8*)&H2[(size_t)grow * 64 + q * 16] = lo;
      *(u16x8*)&H2[(size_t)grow * 64 + q * 16 + 8] = hi;
    }
    char* base = (char*)At + r * 128;
    const int sw = (r & 7) << 4;
    *(u16x8*)(base + ((q * 32) ^ sw)) = lo;
    *(u16x8*)(base + ((q * 32 + 16) ^ sw)) = hi;
  }
  __syncthreads();
  const int l = tid & 63, w = tid >> 6;
  const int rowb = w * 16 + (l & 15);
  const char* abase = (const char*)At + rowb * 128;
  const int sw = (rowb & 7) << 4;
  const int kb = (l >> 4) << 4;
  const s16x8 a0 = *(const s16x8*)(abase + (kb ^ sw));
  const s16x8 a1 = *(const s16x8*)(abase + ((64 + kb) ^ sw));
  const u16x8* wp = (const u16x8*)WP3;
#pragma unroll 4
  for (int ct = 0; ct < 16; ++ct) {
    s16x8 b0 = (s16x8)wp[(ct * 2 + 0) * 64 + l];
    s16x8 b1 = (s16x8)wp[(ct * 2 + 1) * 64 + l];
    f32x4 acc = {0.f, 0.f, 0.f, 0.f};
    acc = mfma16(a0, b0, acc);
    acc = mfma16(a1, b1, acc);
    float sp = acc[0] + acc[1] + acc[2] + acc[3];
    float qp = acc[0] * acc[0] + acc[1] * acc[1] + acc[2] * acc[2] + acc[3] * acc[3];
    sp += __shfl_xor(sp, 16); sp += __shfl_xor(sp, 32);
    qp += __shfl_xor(qp, 16); qp += __shfl_xor(qp, 32);
    if ((l >> 4) == 0) {
      atomicAdd(&lsum[ct * 16 + (l & 15)], sp);
      atomicAdd(&lsq[ct * 16 + (l & 15)], qp);
    }
  }
  __syncthreads();
  for (int i = tid; i < 256; i += 256) {
    atomicAdd(&gsum[i], lsum[i]);
    atomicAdd(&gsq[i], lsq[i]);
  }
}

// ---- K5: out = relu(h2@W3s + X@Wss + cc) -----------------------------------
__global__ __launch_bounds__(256) void kFinal(const ushort* __restrict__ H2,
                                              const float* __restrict__ X,
                                              const ushort* __restrict__ WP3s,
                                              const ushort* __restrict__ WPSs,
                                              const float* __restrict__ ccv,
                                              float* __restrict__ OUT, int N) {
  __shared__ ushort Ah[64 * 64];
  __shared__ ushort Ax[64 * 64];
  const int tid = threadIdx.x;
  const int row0 = blockIdx.x * 64;
  {
    const int r = tid >> 2, q = tid & 3;
    const int grow = row0 + r;
    u16x8 lo = {0, 0, 0, 0, 0, 0, 0, 0}, hi = {0, 0, 0, 0, 0, 0, 0, 0};
    if (grow < N) {
      const u16x8* hp = (const u16x8*)&H2[(size_t)grow * 64 + q * 16];
      lo = hp[0];
      hi = hp[1];
    }
    char* base = (char*)Ah + r * 128;
    const int sw = (r & 7) << 4;
    *(u16x8*)(base + ((q * 32) ^ sw)) = lo;
    *(u16x8*)(base + ((q * 32 + 16) ^ sw)) = hi;
  }
  stageF32(Ax, X, row0, N, tid, 0.f);
  __syncthreads();
  const int l = tid & 63, w = tid >> 6;
  const int rowb = w * 16 + (l & 15);
  const int sw = (rowb & 7) << 4;
  const int kb = (l >> 4) << 4;
  const char* hb = (const char*)Ah + rowb * 128;
  const char* xb = (const char*)Ax + rowb * 128;
  const s16x8 ah0 = *(const s16x8*)(hb + (kb ^ sw));
  const s16x8 ah1 = *(const s16x8*)(hb + ((64 + kb) ^ sw));
  const s16x8 ax0 = *(const s16x8*)(xb + (kb ^ sw));
  const s16x8 ax1 = *(const s16x8*)(xb + ((64 + kb) ^ sw));
  const u16x8* wp3 = (const u16x8*)WP3s;
  const u16x8* wps = (const u16x8*)WPSs;
#pragma unroll 4
  for (int ct = 0; ct < 16; ++ct) {
    s16x8 b0 = (s16x8)wp3[(ct * 2 + 0) * 64 + l];
    s16x8 b1 = (s16x8)wp3[(ct * 2 + 1) * 64 + l];
    s16x8 s0 = (s16x8)wps[(ct * 2 + 0) * 64 + l];
    s16x8 s1 = (s16x8)wps[(ct * 2 + 1) * 64 + l];
    f32x4 acc = {0.f, 0.f, 0.f, 0.f};
    acc = mfma16(ah0, b0, acc);
    acc = mfma16(ah1, b1, acc);
    acc = mfma16(ax0, s0, acc);
    acc = mfma16(ax1, s1, acc);
    const int col = ct * 16 + (l & 15);
    const float cj = ccv[col];
#pragma unroll
    for (int reg = 0; reg < 4; ++reg) {
      const int grow = row0 + w * 16 + ((l >> 4) << 2) + reg;
      if (grow < N) OUT[(size_t)grow * 256 + col] = fmaxf(acc[reg] + cj, 0.f);
    }
  }
}

extern "C" void kernel_launch(void* const* d_in, const int* in_sizes, int n_in,
                              void* d_out, int out_size, void* d_ws, size_t ws_size,
                              hipStream_t stream) {
  const float* X  = (const float*)d_in[0];
  const int*   nbr = (const int*)d_in[1];
  const float* W1 = (const float*)d_in[2];
  const float* g1 = (const float*)d_in[3];
  const float* b1 = (const float*)d_in[4];
  const float* Wk = (const float*)d_in[5];
  const float* g2 = (const float*)d_in[6];
  const float* b2 = (const float*)d_in[7];
  const float* W3 = (const float*)d_in[8];
  const float* g3 = (const float*)d_in[9];
  const float* b3 = (const float*)d_in[10];
  const float* Ws = (const float*)d_in[11];
  const float* gs = (const float*)d_in[12];
  const float* bs = (const float*)d_in[13];
  float* out = (float*)d_out;
  float* ws  = (float*)d_ws;

  const int N = in_sizes[0] / 64;
  const float invN = 1.f / (float)N;

  // ws layout (float offsets)
  float* sum1S = ws + 0;     // [320] (0..63 = Y1, 64..319 = Ys)
  float* sq1S  = ws + 320;   // [320]
  float* sum2  = ws + 640;   // [64]
  float* sq2   = ws + 704;   // [64]
  float* sum3  = ws + 768;   // [256]
  float* sq3   = ws + 1024;  // [256]
  float* a1p = ws + 1280, *c1p = ws + 1344;
  float* aSp = ws + 1408, *cSp = ws + 1664;
  float* a2p = ws + 1920, *c2p = ws + 1984;
  float* a3p = ws + 2048, *c3p = ws + 2304;
  float* ccp = ws + 2560;                         // [256]
  ushort* WP1S = (ushort*)(ws + 2816);            // 20480 bf16
  ushort* WPkP = (ushort*)(ws + 13056);           // 36864 bf16
  ushort* WP3P = (ushort*)(ws + 31488);           // 16384 bf16
  ushort* WP3s = (ushort*)(ws + 39680);           // 16384 bf16
  ushort* WPSs = (ushort*)(ws + 47872);           // 16384 bf16
  ushort* H2b  = (ushort*)(ws + 56064);           // N*64 bf16 (~33 MB)
  // scratch in d_out (dead before kFinal writes)
  ushort* H1b = (ushort*)out;                     // N*64 bf16
  float*  Y2  = out + (size_t)N * 32;             // N*64 f32

  const int gb64 = (N + 63) / 64;

  kZero<<<5, 256, 0, stream>>>(ws, 1280);
  kPackW<<<288, 256, 0, stream>>>(W1, Ws, Wk, W3, WP1S, WPkP, WP3P);
  kStatsXW<<<gb64, 256, 0, stream>>>(X, WP1S, sum1S, sq1S, N);
  kFinStats<<<1, 64, 0, stream>>>(sum1S, sq1S, g1, b1, invN, a1p, c1p, 64);
  kFinStats<<<4, 64, 0, stream>>>(sum1S + 64, sq1S + 64, gs, bs, invN, aSp, cSp, 256);
  kGemm1<<<gb64, 256, 0, stream>>>(X, WP1S, a1p, c1p, H1b, N);
  kConv<<<gb64, 256, 0, stream>>>(H1b, nbr, WPkP, Y2, sum2, sq2, N);
  kFinStats<<<1, 64, 0, stream>>>(sum2, sq2, g2, b2, invN, a2p, c2p, 64);
  kH2S3<<<gb64, 256, 0, stream>>>(Y2, a2p, c2p, WP3P, H2b, sum3, sq3, N);
  kFinStats<<<4, 64, 0, stream>>>(sum3, sq3, g3, b3, invN, a3p, c3p, 256);
  kPackScaled<<<64, 256, 0, stream>>>(W3, Ws, a3p, aSp, c3p, cSp, WP3s, WPSs, ccp);
  kFinal<<<gb64, 256, 0, stream>>>(H2b, X, WP3s, WPSs, ccp, out, N);
}

// Round 4
// 506.122 us; speedup vs baseline: 1.0038x; 1.0038x over previous
//
#include <hip/hip_runtime.h>

typedef __attribute__((ext_vector_type(8))) short  s16x8;
typedef __attribute__((ext_vector_type(8))) unsigned short u16x8;
typedef __attribute__((ext_vector_type(4))) float  f32x4;

constexpr float BN_EPS = 1e-5f;
#define DEV_INLINE __device__ __forceinline__

DEV_INLINE ushort f2bf(float f) {
  unsigned int u = __float_as_uint(f);
  return (ushort)((u + 0x7FFFu + ((u >> 16) & 1u)) >> 16);
}

DEV_INLINE f32x4 mfma16(s16x8 a, s16x8 b, f32x4 c) {
  return __builtin_amdgcn_mfma_f32_16x16x32_bf16(a, b, c, 0, 0, 0);
}

// packed B-fragment index decode: r in [0,1024) -> (k, col16)
DEV_INLINE void decode_frag(int r, int& k, int& c16) {
  const int ks = r >> 9;
  const int l = (r >> 3) & 63;
  const int j = r & 7;
  k = ks * 32 + ((l >> 4) << 3) + j;
  c16 = l & 15;
}

__global__ void kZero(float* p, int n) {
  int i = blockIdx.x * blockDim.x + threadIdx.x;
  if (i < n) p[i] = 0.f;
}

// ---- pack W1|Ws (20 ct), Wk (9 taps x 4 ct), W3 (16 ct) into B-fragment order
__global__ void kPackW(const float* __restrict__ W1, const float* __restrict__ Ws,
                       const float* __restrict__ Wk, const float* __restrict__ W3,
                       ushort* __restrict__ WP1S, ushort* __restrict__ WPk,
                       ushort* __restrict__ WP3) {
  int e = blockIdx.x * 256 + threadIdx.x;  // 73728 total
  if (e < 20480) {
    int ct = e >> 10, r = e & 1023, k, c16;
    decode_frag(r, k, c16);
    float w = (ct < 4) ? W1[k * 64 + ct * 16 + c16] : Ws[k * 256 + (ct - 4) * 16 + c16];
    WP1S[e] = f2bf(w);
  } else if (e < 57344) {
    int e2 = e - 20480;
    int tap = e2 >> 12, r2 = e2 & 4095;
    int ct = r2 >> 10, k, c16;
    decode_frag(r2 & 1023, k, c16);
    WPk[e2] = f2bf(Wk[tap * 4096 + k * 64 + ct * 16 + c16]);
  } else {
    int e3 = e - 57344;
    int ct = e3 >> 10, k, c16;
    decode_frag(e3 & 1023, k, c16);
    WP3[e3] = f2bf(W3[k * 256 + ct * 16 + c16]);
  }
}

// ---- finalize BN affine params from col sums -------------------------------
__global__ void kFinStats(const float* __restrict__ sum, const float* __restrict__ sq,
                          const float* __restrict__ g, const float* __restrict__ b,
                          float invN, float* __restrict__ a, float* __restrict__ c, int n) {
  int j = blockIdx.x * blockDim.x + threadIdx.x;
  if (j < n) {
    float m = sum[j] * invN;
    float v = fmaxf(sq[j] * invN - m * m, 0.f);
    float al = g[j] * rsqrtf(v + BN_EPS);
    a[j] = al;
    c[j] = fmaf(-m, al, b[j]);
  }
}

// ---- pack scaled W3*diag(a3), Ws*diag(aS); cc = c3+cS ----------------------
__global__ void kPackScaled(const float* __restrict__ W3, const float* __restrict__ Ws,
                            const float* __restrict__ a3v, const float* __restrict__ aSv,
                            const float* __restrict__ c3v, const float* __restrict__ cSv,
                            ushort* __restrict__ WP3s, ushort* __restrict__ WPSs,
                            float* __restrict__ cc) {
  int e = blockIdx.x * 256 + threadIdx.x;  // 16384
  int ct = e >> 10, k, c16;
  decode_frag(e & 1023, k, c16);
  int col = ct * 16 + c16;
  WP3s[e] = f2bf(W3[k * 256 + col] * a3v[col]);
  WPSs[e] = f2bf(Ws[k * 256 + col] * aSv[col]);
  if (e < 256) cc[e] = c3v[e] + cSv[e];
}

// ---- stage one 64-row f32 tile into swizzled bf16 LDS ----------------------
// thread t handles row r=t>>2, cols [q*16, q*16+16)
DEV_INLINE void stageF32(ushort* At, const float* __restrict__ src, int row0, int N,
                         int tid, float scale_dummy) {
  const int r = tid >> 2, q = tid & 3;
  const int grow = row0 + r;
  u16x8 lo = {0, 0, 0, 0, 0, 0, 0, 0}, hi = {0, 0, 0, 0, 0, 0, 0, 0};
  if (grow < N) {
    const float4* xp = reinterpret_cast<const float4*>(&src[(size_t)grow * 64 + q * 16]);
#pragma unroll
    for (int i = 0; i < 2; ++i) {
      float4 t = xp[i];
      lo[4 * i + 0] = f2bf(t.x); lo[4 * i + 1] = f2bf(t.y);
      lo[4 * i + 2] = f2bf(t.z); lo[4 * i + 3] = f2bf(t.w);
      float4 u = xp[i + 2];
      hi[4 * i + 0] = f2bf(u.x); hi[4 * i + 1] = f2bf(u.y);
      hi[4 * i + 2] = f2bf(u.z); hi[4 * i + 3] = f2bf(u.w);
    }
  }
  char* base = (char*)At + r * 128;
  const int sw = (r & 7) << 4;
  *(u16x8*)(base + ((q * 32) ^ sw)) = lo;
  *(u16x8*)(base + ((q * 32 + 16) ^ sw)) = hi;
}

// ---- K1: colsum/colsq of X@[W1|Ws] (320 cols), no Y store ------------------
__global__ __launch_bounds__(256) void kStatsXW(const float* __restrict__ X,
                                                const ushort* __restrict__ WP,
                                                float* __restrict__ gsum,
                                                float* __restrict__ gsq, int N) {
  __shared__ ushort At[64 * 64];
  __shared__ float lsum[320], lsq[320];
  const int tid = threadIdx.x;
  const int row0 = blockIdx.x * 64;
  for (int i = tid; i < 320; i += 256) { lsum[i] = 0.f; lsq[i] = 0.f; }
  stageF32(At, X, row0, N, tid, 0.f);
  __syncthreads();
  const int l = tid & 63, w = tid >> 6;
  const int rowb = w * 16 + (l & 15);
  const char* abase = (const char*)At + rowb * 128;
  const int sw = (rowb & 7) << 4;
  const int kb = (l >> 4) << 4;
  const s16x8 a0 = *(const s16x8*)(abase + (kb ^ sw));
  const s16x8 a1 = *(const s16x8*)(abase + ((64 + kb) ^ sw));
  const u16x8* wp = (const u16x8*)WP;
#pragma unroll 5
  for (int ct = 0; ct < 20; ++ct) {
    s16x8 b0 = (s16x8)wp[(ct * 2 + 0) * 64 + l];
    s16x8 b1 = (s16x8)wp[(ct * 2 + 1) * 64 + l];
    f32x4 acc = {0.f, 0.f, 0.f, 0.f};
    acc = mfma16(a0, b0, acc);
    acc = mfma16(a1, b1, acc);
    float sp = acc[0] + acc[1] + acc[2] + acc[3];
    float qp = acc[0] * acc[0] + acc[1] * acc[1] + acc[2] * acc[2] + acc[3] * acc[3];
    sp += __shfl_xor(sp, 16); sp += __shfl_xor(sp, 32);
    qp += __shfl_xor(qp, 16); qp += __shfl_xor(qp, 32);
    if ((l >> 4) == 0) {
      atomicAdd(&lsum[ct * 16 + (l & 15)], sp);
      atomicAdd(&lsq[ct * 16 + (l & 15)], qp);
    }
  }
  __syncthreads();
  for (int i = tid; i < 320; i += 256) {
    atomicAdd(&gsum[i], lsum[i]);
    atomicAdd(&gsq[i], lsq[i]);
  }
}

// ---- K2: h1 = relu(a1*(X@W1)+c1) -> bf16 -----------------------------------
__global__ __launch_bounds__(256) void kGemm1(const float* __restrict__ X,
                                              const ushort* __restrict__ WP,
                                              const float* __restrict__ av,
                                              const float* __restrict__ cv,
                                              ushort* __restrict__ H1, int N) {
  __shared__ ushort At[64 * 64];
  const int tid = threadIdx.x;
  const int row0 = blockIdx.x * 64;
  stageF32(At, X, row0, N, tid, 0.f);
  __syncthreads();
  const int l = tid & 63, w = tid >> 6;
  const int rowb = w * 16 + (l & 15);
  const char* abase = (const char*)At + rowb * 128;
  const int sw = (rowb & 7) << 4;
  const int kb = (l >> 4) << 4;
  const s16x8 a0 = *(const s16x8*)(abase + (kb ^ sw));
  const s16x8 a1 = *(const s16x8*)(abase + ((64 + kb) ^ sw));
  const u16x8* wp = (const u16x8*)WP;
#pragma unroll
  for (int ct = 0; ct < 4; ++ct) {
    s16x8 b0 = (s16x8)wp[(ct * 2 + 0) * 64 + l];
    s16x8 b1 = (s16x8)wp[(ct * 2 + 1) * 64 + l];
    f32x4 acc = {0.f, 0.f, 0.f, 0.f};
    acc = mfma16(a0, b0, acc);
    acc = mfma16(a1, b1, acc);
    const int col = ct * 16 + (l & 15);
    const float aj = av[col], cj = cv[col];
#pragma unroll
    for (int reg = 0; reg < 4; ++reg) {
      const int grow = row0 + w * 16 + ((l >> 4) << 2) + reg;
      if (grow < N) H1[(size_t)grow * 64 + col] = f2bf(fmaxf(fmaf(acc[reg], aj, cj), 0.f));
    }
  }
}

// ---- K3: Y2 = sum_k gather_k(h1) @ Wk[k] (MFMA) + BN2 col stats ------------
__global__ __launch_bounds__(256) void kConv(const ushort* __restrict__ H1,
                                             const int* __restrict__ nbr,
                                             const ushort* __restrict__ WPk,
                                             float* __restrict__ Y2,
                                             float* __restrict__ gsum,
                                             float* __restrict__ gsq, int N) {
  __shared__ ushort At[64 * 64];
  __shared__ int idx[576];
  __shared__ float lsum[64], lsq[64];
  const int tid = threadIdx.x;
  const int row0 = blockIdx.x * 64;
  if (tid < 64) { lsum[tid] = 0.f; lsq[tid] = 0.f; }
  for (int e = tid; e < 576; e += 256) {
    const int grow = row0 + e / 9;
    idx[e] = (grow < N) ? nbr[(size_t)row0 * 9 + e] : -1;
  }
  const int l = tid & 63, w = tid >> 6;
  const int rowb = w * 16 + (l & 15);
  const char* abase = (const char*)At + rowb * 128;
  const int swr = (rowb & 7) << 4;
  const int kb = (l >> 4) << 4;
  const int r = tid >> 2, q = tid & 3;
  char* wbase = (char*)At + r * 128;
  const int sww = (r & 7) << 4;
  f32x4 acc[4];
#pragma unroll
  for (int ct = 0; ct < 4; ++ct) acc[ct] = {0.f, 0.f, 0.f, 0.f};
  const u16x8* wp = (const u16x8*)WPk;
  for (int k = 0; k < 9; ++k) {
    __syncthreads();  // idx ready (k=0) / prev reads done
    const int src = idx[r * 9 + k];
    u16x8 lo = {0, 0, 0, 0, 0, 0, 0, 0}, hi = {0, 0, 0, 0, 0, 0, 0, 0};
    if (src >= 0) {
      const u16x8* hp = (const u16x8*)&H1[(size_t)src * 64 + q * 16];
      lo = hp[0];
      hi = hp[1];
    }
    *(u16x8*)(wbase + ((q * 32) ^ sww)) = lo;
    *(u16x8*)(wbase + ((q * 32 + 16) ^ sww)) = hi;
    __syncthreads();
    const s16x8 a0 = *(const s16x8*)(abase + (kb ^ swr));
    const s16x8 a1 = *(const s16x8*)(abase + ((64 + kb) ^ swr));
#pragma unroll
    for (int ct = 0; ct < 4; ++ct) {
      s16x8 b0 = (s16x8)wp[((size_t)((k * 4 + ct) * 2 + 0)) * 64 + l];
      s16x8 b1 = (s16x8)wp[((size_t)((k * 4 + ct) * 2 + 1)) * 64 + l];
      acc[ct] = mfma16(a0, b0, acc[ct]);
      acc[ct] = mfma16(a1, b1, acc[ct]);
    }
  }
#pragma unroll
  for (int ct = 0; ct < 4; ++ct) {
    const f32x4 v = acc[ct];
    const int col = ct * 16 + (l & 15);
#pragma unroll
    for (int reg = 0; reg < 4; ++reg) {
      const int grow = row0 + w * 16 + ((l >> 4) << 2) + reg;
      if (grow < N) Y2[(size_t)grow * 64 + col] = v[reg];
    }
    float sp = v[0] + v[1] + v[2] + v[3];
    float qp = v[0] * v[0] + v[1] * v[1] + v[2] * v[2] + v[3] * v[3];
    sp += __shfl_xor(sp, 16); sp += __shfl_xor(sp, 32);
    qp += __shfl_xor(qp, 16); qp += __shfl_xor(qp, 32);
    if ((l >> 4) == 0) {
      atomicAdd(&lsum[col], sp);
      atomicAdd(&lsq[col], qp);
    }
  }
  __syncthreads();
  if (tid < 64) {
    atomicAdd(&gsum[tid], lsum[tid]);
    atomicAdd(&gsq[tid], lsq[tid]);
  }
}

// ---- K4: h2 = relu(a2*Y2+c2) -> bf16 store + BN3 stats (h2@W3) -------------
__global__ __launch_bounds__(256) void kH2S3(const float* __restrict__ Y2,
                                             const float* __restrict__ a2v,
                                             const float* __restrict__ c2v,
                                             const ushort* __restrict__ WP3,
                                             ushort* __restrict__ H2,
                                             float* __restrict__ gsum,
                                             float* __restrict__ gsq, int N) {
  __shared__ ushort At[64 * 64];
  __shared__ float lsum[256], lsq[256];
  __shared__ float a2s[64], c2s[64];
  const int tid = threadIdx.x;
  const int row0 = blockIdx.x * 64;
  for (int i = tid; i < 256; i += 256) { lsum[i] = 0.f; lsq[i] = 0.f; }
  if (tid < 64) a2s[tid] = a2v[tid];
  else if (tid < 128) c2s[tid - 64] = c2v[tid - 64];
  __syncthreads();
  {
    const int r = tid >> 2, q = tid & 3;
    const int grow = row0 + r;
    u16x8 lo = {0, 0, 0, 0, 0, 0, 0, 0}, hi = {0, 0, 0, 0, 0, 0, 0, 0};
    if (grow < N) {
      const float4* yp = reinterpret_cast<const float4*>(&Y2[(size_t)grow * 64 + q * 16]);
#pragma unroll
      for (int i = 0; i < 2; ++i) {
        float4 t = yp[i];
        float4 u = yp[i + 2];
        const int cb = q * 16;
        lo[4 * i + 0] = f2bf(fmaxf(fmaf(t.x, a2s[cb + 4 * i + 0], c2s[cb + 4 * i + 0]), 0.f));
        lo[4 * i + 1] = f2bf(fmaxf(fmaf(t.y, a2s[cb + 4 * i + 1], c2s[cb + 4 * i + 1]), 0.f));
        lo[4 * i + 2] = f2bf(fmaxf(fmaf(t.z, a2s[cb + 4 * i + 2], c2s[cb + 4 * i + 2]), 0.f));
        lo[4 * i + 3] = f2bf(fmaxf(fmaf(t.w, a2s[cb + 4 * i + 3], c2s[cb + 4 * i + 3]), 0.f));
        hi[4 * i + 0] = f2bf(fmaxf(fmaf(u.x, a2s[cb + 8 + 4 * i + 0], c2s[cb + 8 + 4 * i + 0]), 0.f));
        hi[4 * i + 1] = f2bf(fmaxf(fmaf(u.y, a2s[cb + 8 + 4 * i + 1], c2s[cb + 8 + 4 * i + 1]), 0.f));
        hi[4 * i + 2] = f2bf(fmaxf(fmaf(u.z, a2s[cb + 8 + 4 * i + 2], c2s[cb + 8 + 4 * i + 2]), 0.f));
        hi[4 * i + 3] = f2bf(fmaxf(fmaf(u.w, a2s[cb + 8 + 4 * i + 3], c2s[cb + 8 + 4 * i + 3]), 0.f));
      }
      *(u16x8*)&H2[(size_t)grow * 64 + q * 16] = lo;
      *(u16x8*)&H2[(size_t)grow * 64 + q * 16 + 8] = hi;
    }
    char* base = (char*)At + r * 128;
    const int sw = (r & 7) << 4;
    *(u16x8*)(base + ((q * 32) ^ sw)) = lo;
    *(u16x8*)(base + ((q * 32 + 16) ^ sw)) = hi;
  }
  __syncthreads();
  const int l = tid & 63, w = tid >> 6;
  const int rowb = w * 16 + (l & 15);
  const char* abase = (const char*)At + rowb * 128;
  const int sw = (rowb & 7) << 4;
  const int kb = (l >> 4) << 4;
  const s16x8 a0 = *(const s16x8*)(abase + (kb ^ sw));
  const s16x8 a1 = *(const s16x8*)(abase + ((64 + kb) ^ sw));
  const u16x8* wp = (const u16x8*)WP3;
#pragma unroll 4
  for (int ct = 0; ct < 16; ++ct) {
    s16x8 b0 = (s16x8)wp[(ct * 2 + 0) * 64 + l];
    s16x8 b1 = (s16x8)wp[(ct * 2 + 1) * 64 + l];
    f32x4 acc = {0.f, 0.f, 0.f, 0.f};
    acc = mfma16(a0, b0, acc);
    acc = mfma16(a1, b1, acc);
    float sp = acc[0] + acc[1] + acc[2] + acc[3];
    float qp = acc[0] * acc[0] + acc[1] * acc[1] + acc[2] * acc[2] + acc[3] * acc[3];
    sp += __shfl_xor(sp, 16); sp += __shfl_xor(sp, 32);
    qp += __shfl_xor(qp, 16); qp += __shfl_xor(qp, 32);
    if ((l >> 4) == 0) {
      atomicAdd(&lsum[ct * 16 + (l & 15)], sp);
      atomicAdd(&lsq[ct * 16 + (l & 15)], qp);
    }
  }
  __syncthreads();
  for (int i = tid; i < 256; i += 256) {
    atomicAdd(&gsum[i], lsum[i]);
    atomicAdd(&gsq[i], lsq[i]);
  }
}

// ---- K5: out = relu(h2@W3s + X@Wss + cc) -----------------------------------
__global__ __launch_bounds__(256) void kFinal(const ushort* __restrict__ H2,
                                              const float* __restrict__ X,
                                              const ushort* __restrict__ WP3s,
                                              const ushort* __restrict__ WPSs,
                                              const float* __restrict__ ccv,
                                              float* __restrict__ OUT, int N) {
  __shared__ ushort Ah[64 * 64];
  __shared__ ushort Ax[64 * 64];
  const int tid = threadIdx.x;
  const int row0 = blockIdx.x * 64;
  {
    const int r = tid >> 2, q = tid & 3;
    const int grow = row0 + r;
    u16x8 lo = {0, 0, 0, 0, 0, 0, 0, 0}, hi = {0, 0, 0, 0, 0, 0, 0, 0};
    if (grow < N) {
      const u16x8* hp = (const u16x8*)&H2[(size_t)grow * 64 + q * 16];
      lo = hp[0];
      hi = hp[1];
    }
    char* base = (char*)Ah + r * 128;
    const int sw = (r & 7) << 4;
    *(u16x8*)(base + ((q * 32) ^ sw)) = lo;
    *(u16x8*)(base + ((q * 32 + 16) ^ sw)) = hi;
  }
  stageF32(Ax, X, row0, N, tid, 0.f);
  __syncthreads();
  const int l = tid & 63, w = tid >> 6;
  const int rowb = w * 16 + (l & 15);
  const int sw = (rowb & 7) << 4;
  const int kb = (l >> 4) << 4;
  const char* hb = (const char*)Ah + rowb * 128;
  const char* xb = (const char*)Ax + rowb * 128;
  const s16x8 ah0 = *(const s16x8*)(hb + (kb ^ sw));
  const s16x8 ah1 = *(const s16x8*)(hb + ((64 + kb) ^ sw));
  const s16x8 ax0 = *(const s16x8*)(xb + (kb ^ sw));
  const s16x8 ax1 = *(const s16x8*)(xb + ((64 + kb) ^ sw));
  const u16x8* wp3 = (const u16x8*)WP3s;
  const u16x8* wps = (const u16x8*)WPSs;
#pragma unroll 4
  for (int ct = 0; ct < 16; ++ct) {
    s16x8 b0 = (s16x8)wp3[(ct * 2 + 0) * 64 + l];
    s16x8 b1 = (s16x8)wp3[(ct * 2 + 1) * 64 + l];
    s16x8 s0 = (s16x8)wps[(ct * 2 + 0) * 64 + l];
    s16x8 s1 = (s16x8)wps[(ct * 2 + 1) * 64 + l];
    f32x4 acc = {0.f, 0.f, 0.f, 0.f};
    acc = mfma16(ah0, b0, acc);
    acc = mfma16(ah1, b1, acc);
    acc = mfma16(ax0, s0, acc);
    acc = mfma16(ax1, s1, acc);
    const int col = ct * 16 + (l & 15);
    const float cj = ccv[col];
#pragma unroll
    for (int reg = 0; reg < 4; ++reg) {
      const int grow = row0 + w * 16 + ((l >> 4) << 2) + reg;
      if (grow < N) OUT[(size_t)grow * 256 + col] = fmaxf(acc[reg] + cj, 0.f);
    }
  }
}

extern "C" void kernel_launch(void* const* d_in, const int* in_sizes, int n_in,
                              void* d_out, int out_size, void* d_ws, size_t ws_size,
                              hipStream_t stream) {
  const float* X  = (const float*)d_in[0];
  const int*   nbr = (const int*)d_in[1];
  const float* W1 = (const float*)d_in[2];
  const float* g1 = (const float*)d_in[3];
  const float* b1 = (const float*)d_in[4];
  const float* Wk = (const float*)d_in[5];
  const float* g2 = (const float*)d_in[6];
  const float* b2 = (const float*)d_in[7];
  const float* W3 = (const float*)d_in[8];
  const float* g3 = (const float*)d_in[9];
  const float* b3 = (const float*)d_in[10];
  const float* Ws = (const float*)d_in[11];
  const float* gs = (const float*)d_in[12];
  const float* bs = (const float*)d_in[13];
  float* out = (float*)d_out;
  float* ws  = (float*)d_ws;

  const int N = in_sizes[0] / 64;
  const float invN = 1.f / (float)N;

  // ws layout (float offsets)
  float* sum1S = ws + 0;     // [320] (0..63 = Y1, 64..319 = Ys)
  float* sq1S  = ws + 320;   // [320]
  float* sum2  = ws + 640;   // [64]
  float* sq2   = ws + 704;   // [64]
  float* sum3  = ws + 768;   // [256]
  float* sq3   = ws + 1024;  // [256]
  float* a1p = ws + 1280, *c1p = ws + 1344;
  float* aSp = ws + 1408, *cSp = ws + 1664;
  float* a2p = ws + 1920, *c2p = ws + 1984;
  float* a3p = ws + 2048, *c3p = ws + 2304;
  float* ccp = ws + 2560;                         // [256]
  ushort* WP1S = (ushort*)(ws + 2816);            // 20480 bf16
  ushort* WPkP = (ushort*)(ws + 13056);           // 36864 bf16
  ushort* WP3P = (ushort*)(ws + 31488);           // 16384 bf16
  ushort* WP3s = (ushort*)(ws + 39680);           // 16384 bf16
  ushort* WPSs = (ushort*)(ws + 47872);           // 16384 bf16
  ushort* H2b  = (ushort*)(ws + 56064);           // N*64 bf16 (~33 MB)
  // scratch in d_out (dead before kFinal writes)
  ushort* H1b = (ushort*)out;                     // N*64 bf16
  float*  Y2  = out + (size_t)N * 32;             // N*64 f32

  const int gb64 = (N + 63) / 64;

  kZero<<<5, 256, 0, stream>>>(ws, 1280);
  kPackW<<<288, 256, 0, stream>>>(W1, Ws, Wk, W3, WP1S, WPkP, WP3P);
  kStatsXW<<<gb64, 256, 0, stream>>>(X, WP1S, sum1S, sq1S, N);
  kFinStats<<<1, 64, 0, stream>>>(sum1S, sq1S, g1, b1, invN, a1p, c1p, 64);
  kFinStats<<<4, 64, 0, stream>>>(sum1S + 64, sq1S + 64, gs, bs, invN, aSp, cSp, 256);
  kGemm1<<<gb64, 256, 0, stream>>>(X, WP1S, a1p, c1p, H1b, N);
  kConv<<<gb64, 256, 0, stream>>>(H1b, nbr, WPkP, Y2, sum2, sq2, N);
  kFinStats<<<1, 64, 0, stream>>>(sum2, sq2, g2, b2, invN, a2p, c2p, 64);
  kH2S3<<<gb64, 256, 0, stream>>>(Y2, a2p, c2p, WP3P, H2b, sum3, sq3, N);
  kFinStats<<<4, 64, 0, stream>>>(sum3, sq3, g3, b3, invN, a3p, c3p, 256);
  kPackScaled<<<64, 256, 0, stream>>>(W3, Ws, a3p, aSp, c3p, cSp, WP3s, WPSs, ccp);
  kFinal<<<gb64, 256, 0, stream>>>(H2b, X, WP3s, WPSs, ccp, out, N);
}

// Round 5
// 503.254 us; speedup vs baseline: 1.0095x; 1.0057x over previous
//
#include <hip/hip_runtime.h>

typedef __attribute__((ext_vector_type(8))) short  s16x8;
typedef __attribute__((ext_vector_type(8))) unsigned short u16x8;
typedef __attribute__((ext_vector_type(4))) float  f32x4;

constexpr float BN_EPS = 1e-5f;
#define DEV_INLINE __device__ __forceinline__

DEV_INLINE ushort f2bf(float f) {
  unsigned int u = __float_as_uint(f);
  return (ushort)((u + 0x7FFFu + ((u >> 16) & 1u)) >> 16);
}

DEV_INLINE f32x4 mfma16(s16x8 a, s16x8 b, f32x4 c) {
  return __builtin_amdgcn_mfma_f32_16x16x32_bf16(a, b, c, 0, 0, 0);
}

// packed B-fragment index decode: r in [0,1024) -> (k, col16)
DEV_INLINE void decode_frag(int r, int& k, int& c16) {
  const int ks = r >> 9;
  const int l = (r >> 3) & 63;
  const int j = r & 7;
  k = ks * 32 + ((l >> 4) << 3) + j;
  c16 = l & 15;
}

__global__ void kZero(float* p, int n) {
  int i = blockIdx.x * blockDim.x + threadIdx.x;
  if (i < n) p[i] = 0.f;
}

// ---- pack W1|Ws (20 ct), Wk (9 taps x 4 ct), W3 (16 ct) into B-fragment order
__global__ void kPackW(const float* __restrict__ W1, const float* __restrict__ Ws,
                       const float* __restrict__ Wk, const float* __restrict__ W3,
                       ushort* __restrict__ WP1S, ushort* __restrict__ WPk,
                       ushort* __restrict__ WP3) {
  int e = blockIdx.x * 256 + threadIdx.x;  // 73728 total
  if (e < 20480) {
    int ct = e >> 10, r = e & 1023, k, c16;
    decode_frag(r, k, c16);
    float w = (ct < 4) ? W1[k * 64 + ct * 16 + c16] : Ws[k * 256 + (ct - 4) * 16 + c16];
    WP1S[e] = f2bf(w);
  } else if (e < 57344) {
    int e2 = e - 20480;
    int tap = e2 >> 12, r2 = e2 & 4095;
    int ct = r2 >> 10, k, c16;
    decode_frag(r2 & 1023, k, c16);
    WPk[e2] = f2bf(Wk[tap * 4096 + k * 64 + ct * 16 + c16]);
  } else {
    int e3 = e - 57344;
    int ct = e3 >> 10, k, c16;
    decode_frag(e3 & 1023, k, c16);
    WP3[e3] = f2bf(W3[k * 256 + ct * 16 + c16]);
  }
}

// ---- finalize BN affine params from col sums -------------------------------
__global__ void kFinStats(const float* __restrict__ sum, const float* __restrict__ sq,
                          const float* __restrict__ g, const float* __restrict__ b,
                          float invN, float* __restrict__ a, float* __restrict__ c, int n) {
  int j = blockIdx.x * blockDim.x + threadIdx.x;
  if (j < n) {
    float m = sum[j] * invN;
    float v = fmaxf(sq[j] * invN - m * m, 0.f);
    float al = g[j] * rsqrtf(v + BN_EPS);
    a[j] = al;
    c[j] = fmaf(-m, al, b[j]);
  }
}

// ---- pack scaled W3*diag(a3), Ws*diag(aS); cc = c3+cS ----------------------
__global__ void kPackScaled(const float* __restrict__ W3, const float* __restrict__ Ws,
                            const float* __restrict__ a3v, const float* __restrict__ aSv,
                            const float* __restrict__ c3v, const float* __restrict__ cSv,
                            ushort* __restrict__ WP3s, ushort* __restrict__ WPSs,
                            float* __restrict__ cc) {
  int e = blockIdx.x * 256 + threadIdx.x;  // 16384
  int ct = e >> 10, k, c16;
  decode_frag(e & 1023, k, c16);
  int col = ct * 16 + c16;
  WP3s[e] = f2bf(W3[k * 256 + col] * a3v[col]);
  WPSs[e] = f2bf(Ws[k * 256 + col] * aSv[col]);
  if (e < 256) cc[e] = c3v[e] + cSv[e];
}

// ---- stage one 64-row f32 tile into swizzled bf16 LDS ----------------------
// thread t handles row r=t>>2, cols [q*16, q*16+16)
DEV_INLINE void stageF32(ushort* At, const float* __restrict__ src, int row0, int N,
                         int tid, float scale_dummy) {
  const int r = tid >> 2, q = tid & 3;
  const int grow = row0 + r;
  u16x8 lo = {0, 0, 0, 0, 0, 0, 0, 0}, hi = {0, 0, 0, 0, 0, 0, 0, 0};
  if (grow < N) {
    const float4* xp = reinterpret_cast<const float4*>(&src[(size_t)grow * 64 + q * 16]);
#pragma unroll
    for (int i = 0; i < 2; ++i) {
      float4 t = xp[i];
      lo[4 * i + 0] = f2bf(t.x); lo[4 * i + 1] = f2bf(t.y);
      lo[4 * i + 2] = f2bf(t.z); lo[4 * i + 3] = f2bf(t.w);
      float4 u = xp[i + 2];
      hi[4 * i + 0] = f2bf(u.x); hi[4 * i + 1] = f2bf(u.y);
      hi[4 * i + 2] = f2bf(u.z); hi[4 * i + 3] = f2bf(u.w);
    }
  }
  char* base = (char*)At + r * 128;
  const int sw = (r & 7) << 4;
  *(u16x8*)(base + ((q * 32) ^ sw)) = lo;
  *(u16x8*)(base + ((q * 32 + 16) ^ sw)) = hi;
}

// ---- K1: colsum/colsq of X@[W1|Ws] (320 cols), no Y store ------------------
__global__ __launch_bounds__(256) void kStatsXW(const float* __restrict__ X,
                                                const ushort* __restrict__ WP,
                                                float* __restrict__ gsum,
                                                float* __restrict__ gsq, int N) {
  __shared__ ushort At[64 * 64];
  __shared__ float lsum[320], lsq[320];
  const int tid = threadIdx.x;
  const int row0 = blockIdx.x * 64;
  for (int i = tid; i < 320; i += 256) { lsum[i] = 0.f; lsq[i] = 0.f; }
  stageF32(At, X, row0, N, tid, 0.f);
  __syncthreads();
  const int l = tid & 63, w = tid >> 6;
  const int rowb = w * 16 + (l & 15);
  const char* abase = (const char*)At + rowb * 128;
  const int sw = (rowb & 7) << 4;
  const int kb = (l >> 4) << 4;
  const s16x8 a0 = *(const s16x8*)(abase + (kb ^ sw));
  const s16x8 a1 = *(const s16x8*)(abase + ((64 + kb) ^ sw));
  const u16x8* wp = (const u16x8*)WP;
#pragma unroll 5
  for (int ct = 0; ct < 20; ++ct) {
    s16x8 b0 = (s16x8)wp[(ct * 2 + 0) * 64 + l];
    s16x8 b1 = (s16x8)wp[(ct * 2 + 1) * 64 + l];
    f32x4 acc = {0.f, 0.f, 0.f, 0.f};
    acc = mfma16(a0, b0, acc);
    acc = mfma16(a1, b1, acc);
    float sp = acc[0] + acc[1] + acc[2] + acc[3];
    float qp = acc[0] * acc[0] + acc[1] * acc[1] + acc[2] * acc[2] + acc[3] * acc[3];
    sp += __shfl_xor(sp, 16); sp += __shfl_xor(sp, 32);
    qp += __shfl_xor(qp, 16); qp += __shfl_xor(qp, 32);
    if ((l >> 4) == 0) {
      atomicAdd(&lsum[ct * 16 + (l & 15)], sp);
      atomicAdd(&lsq[ct * 16 + (l & 15)], qp);
    }
  }
  __syncthreads();
  for (int i = tid; i < 320; i += 256) {
    atomicAdd(&gsum[i], lsum[i]);
    atomicAdd(&gsq[i], lsq[i]);
  }
}

// ---- K2: h1 = relu(a1*(X@W1)+c1) -> bf16 -----------------------------------
__global__ __launch_bounds__(256) void kGemm1(const float* __restrict__ X,
                                              const ushort* __restrict__ WP,
                                              const float* __restrict__ av,
                                              const float* __restrict__ cv,
                                              ushort* __restrict__ H1, int N) {
  __shared__ ushort At[64 * 64];
  const int tid = threadIdx.x;
  const int row0 = blockIdx.x * 64;
  stageF32(At, X, row0, N, tid, 0.f);
  __syncthreads();
  const int l = tid & 63, w = tid >> 6;
  const int rowb = w * 16 + (l & 15);
  const char* abase = (const char*)At + rowb * 128;
  const int sw = (rowb & 7) << 4;
  const int kb = (l >> 4) << 4;
  const s16x8 a0 = *(const s16x8*)(abase + (kb ^ sw));
  const s16x8 a1 = *(const s16x8*)(abase + ((64 + kb) ^ sw));
  const u16x8* wp = (const u16x8*)WP;
#pragma unroll
  for (int ct = 0; ct < 4; ++ct) {
    s16x8 b0 = (s16x8)wp[(ct * 2 + 0) * 64 + l];
    s16x8 b1 = (s16x8)wp[(ct * 2 + 1) * 64 + l];
    f32x4 acc = {0.f, 0.f, 0.f, 0.f};
    acc = mfma16(a0, b0, acc);
    acc = mfma16(a1, b1, acc);
    const int col = ct * 16 + (l & 15);
    const float aj = av[col], cj = cv[col];
#pragma unroll
    for (int reg = 0; reg < 4; ++reg) {
      const int grow = row0 + w * 16 + ((l >> 4) << 2) + reg;
      if (grow < N) H1[(size_t)grow * 64 + col] = f2bf(fmaxf(fmaf(acc[reg], aj, cj), 0.f));
    }
  }
}

// ---- K3: Y2 = sum_k gather_k(h1) @ Wk[k] (MFMA) + BN2 col stats ------------
__global__ __launch_bounds__(256) void kConv(const ushort* __restrict__ H1,
                                             const int* __restrict__ nbr,
                                             const ushort* __restrict__ WPk,
                                             float* __restrict__ Y2,
                                             float* __restrict__ gsum,
                                             float* __restrict__ gsq, int N) {
  __shared__ ushort At[64 * 64];
  __shared__ int idx[576];
  __shared__ float lsum[64], lsq[64];
  const int tid = threadIdx.x;
  const int row0 = blockIdx.x * 64;
  if (tid < 64) { lsum[tid] = 0.f; lsq[tid] = 0.f; }
  for (int e = tid; e < 576; e += 256) {
    const int grow = row0 + e / 9;
    idx[e] = (grow < N) ? nbr[(size_t)row0 * 9 + e] : -1;
  }
  const int l = tid & 63, w = tid >> 6;
  const int rowb = w * 16 + (l & 15);
  const char* abase = (const char*)At + rowb * 128;
  const int swr = (rowb & 7) << 4;
  const int kb = (l >> 4) << 4;
  const int r = tid >> 2, q = tid & 3;
  char* wbase = (char*)At + r * 128;
  const int sww = (r & 7) << 4;
  f32x4 acc[4];
#pragma unroll
  for (int ct = 0; ct < 4; ++ct) acc[ct] = {0.f, 0.f, 0.f, 0.f};
  const u16x8* wp = (const u16x8*)WPk;
  for (int k = 0; k < 9; ++k) {
    __syncthreads();  // idx ready (k=0) / prev reads done
    const int src = idx[r * 9 + k];
    u16x8 lo = {0, 0, 0, 0, 0, 0, 0, 0}, hi = {0, 0, 0, 0, 0, 0, 0, 0};
    if (src >= 0) {
      const u16x8* hp = (const u16x8*)&H1[(size_t)src * 64 + q * 16];
      lo = hp[0];
      hi = hp[1];
    }
    *(u16x8*)(wbase + ((q * 32) ^ sww)) = lo;
    *(u16x8*)(wbase + ((q * 32 + 16) ^ sww)) = hi;
    __syncthreads();
    const s16x8 a0 = *(const s16x8*)(abase + (kb ^ swr));
    const s16x8 a1 = *(const s16x8*)(abase + ((64 + kb) ^ swr));
#pragma unroll
    for (int ct = 0; ct < 4; ++ct) {
      s16x8 b0 = (s16x8)wp[((size_t)((k * 4 + ct) * 2 + 0)) * 64 + l];
      s16x8 b1 = (s16x8)wp[((size_t)((k * 4 + ct) * 2 + 1)) * 64 + l];
      acc[ct] = mfma16(a0, b0, acc[ct]);
      acc[ct] = mfma16(a1, b1, acc[ct]);
    }
  }
#pragma unroll
  for (int ct = 0; ct < 4; ++ct) {
    const f32x4 v = acc[ct];
    const int col = ct * 16 + (l & 15);
#pragma unroll
    for (int reg = 0; reg < 4; ++reg) {
      const int grow = row0 + w * 16 + ((l >> 4) << 2) + reg;
      if (grow < N) Y2[(size_t)grow * 64 + col] = v[reg];
    }
    float sp = v[0] + v[1] + v[2] + v[3];
    float qp = v[0] * v[0] + v[1] * v[1] + v[2] * v[2] + v[3] * v[3];
    sp += __shfl_xor(sp, 16); sp += __shfl_xor(sp, 32);
    qp += __shfl_xor(qp, 16); qp += __shfl_xor(qp, 32);
    if ((l >> 4) == 0) {
      atomicAdd(&lsum[col], sp);
      atomicAdd(&lsq[col], qp);
    }
  }
  __syncthreads();
  if (tid < 64) {
    atomicAdd(&gsum[tid], lsum[tid]);
    atomicAdd(&gsq[tid], lsq[tid]);
  }
}

// ---- K4: h2 = relu(a2*Y2+c2) -> bf16 store + BN3 stats (h2@W3) -------------
__global__ __launch_bounds__(256) void kH2S3(const float* __restrict__ Y2,
                                             const float* __restrict__ a2v,
                                             const float* __restrict__ c2v,
                                             const ushort* __restrict__ WP3,
                                             ushort* __restrict__ H2,
                                             float* __restrict__ gsum,
                                             float* __restrict__ gsq, int N) {
  __shared__ ushort At[64 * 64];
  __shared__ float lsum[256], lsq[256];
  __shared__ float a2s[64], c2s[64];
  const int tid = threadIdx.x;
  const int row0 = blockIdx.x * 64;
  for (int i = tid; i < 256; i += 256) { lsum[i] = 0.f; lsq[i] = 0.f; }
  if (tid < 64) a2s[tid] = a2v[tid];
  else if (tid < 128) c2s[tid - 64] = c2v[tid - 64];
  __syncthreads();
  {
    const int r = tid >> 2, q = tid & 3;
    const int grow = row0 + r;
    u16x8 lo = {0, 0, 0, 0, 0, 0, 0, 0}, hi = {0, 0, 0, 0, 0, 0, 0, 0};
    if (grow < N) {
      const float4* yp = reinterpret_cast<const float4*>(&Y2[(size_t)grow * 64 + q * 16]);
#pragma unroll
      for (int i = 0; i < 2; ++i) {
        float4 t = yp[i];
        float4 u = yp[i + 2];
        const int cb = q * 16;
        lo[4 * i + 0] = f2bf(fmaxf(fmaf(t.x, a2s[cb + 4 * i + 0], c2s[cb + 4 * i + 0]), 0.f));
        lo[4 * i + 1] = f2bf(fmaxf(fmaf(t.y, a2s[cb + 4 * i + 1], c2s[cb + 4 * i + 1]), 0.f));
        lo[4 * i + 2] = f2bf(fmaxf(fmaf(t.z, a2s[cb + 4 * i + 2], c2s[cb + 4 * i + 2]), 0.f));
        lo[4 * i + 3] = f2bf(fmaxf(fmaf(t.w, a2s[cb + 4 * i + 3], c2s[cb + 4 * i + 3]), 0.f));
        hi[4 * i + 0] = f2bf(fmaxf(fmaf(u.x, a2s[cb + 8 + 4 * i + 0], c2s[cb + 8 + 4 * i + 0]), 0.f));
        hi[4 * i + 1] = f2bf(fmaxf(fmaf(u.y, a2s[cb + 8 + 4 * i + 1], c2s[cb + 8 + 4 * i + 1]), 0.f));
        hi[4 * i + 2] = f2bf(fmaxf(fmaf(u.z, a2s[cb + 8 + 4 * i + 2], c2s[cb + 8 + 4 * i + 2]), 0.f));
        hi[4 * i + 3] = f2bf(fmaxf(fmaf(u.w, a2s[cb + 8 + 4 * i + 3], c2s[cb + 8 + 4 * i + 3]), 0.f));
      }
      *(u16x8*)&H2[(size_t)grow * 64 + q * 16] = lo;
      *(u16x8*)&H2[(size_t)grow * 64 + q * 16 + 8] = hi;
    }
    char* base = (char*)At + r * 128;
    const int sw = (r & 7) << 4;
    *(u16x8*)(base + ((q * 32) ^ sw)) = lo;
    *(u16x8*)(base + ((q * 32 + 16) ^ sw)) = hi;
  }
  __syncthreads();
  const int l = tid & 63, w = tid >> 6;
  const int rowb = w * 16 + (l & 15);
  const char* abase = (const char*)At + rowb * 128;
  const int sw = (rowb & 7) << 4;
  const int kb = (l >> 4) << 4;
  const s16x8 a0 = *(const s16x8*)(abase + (kb ^ sw));
  const s16x8 a1 = *(const s16x8*)(abase + ((64 + kb) ^ sw));
  const u16x8* wp = (const u16x8*)WP3;
#pragma unroll 4
  for (int ct = 0; ct < 16; ++ct) {
    s16x8 b0 = (s16x8)wp[(ct * 2 + 0) * 64 + l];
    s16x8 b1 = (s16x8)wp[(ct * 2 + 1) * 64 + l];
    f32x4 acc = {0.f, 0.f, 0.f, 0.f};
    acc = mfma16(a0, b0, acc);
    acc = mfma16(a1, b1, acc);
    float sp = acc[0] + acc[1] + acc[2] + acc[3];
    float qp = acc[0] * acc[0] + acc[1] * acc[1] + acc[2] * acc[2] + acc[3] * acc[3];
    sp += __shfl_xor(sp, 16); sp += __shfl_xor(sp, 32);
    qp += __shfl_xor(qp, 16); qp += __shfl_xor(qp, 32);
    if ((l >> 4) == 0) {
      atomicAdd(&lsum[ct * 16 + (l & 15)], sp);
      atomicAdd(&lsq[ct * 16 + (l & 15)], qp);
    }
  }
  __syncthreads();
  for (int i = tid; i < 256; i += 256) {
    atomicAdd(&gsum[i], lsum[i]);
    atomicAdd(&gsq[i], lsq[i]);
  }
}

// ---- K5: out = relu(h2@W3s + X@Wss + cc) -----------------------------------
__global__ __launch_bounds__(256) void kFinal(const ushort* __restrict__ H2,
                                              const float* __restrict__ X,
                                              const ushort* __restrict__ WP3s,
                                              const ushort* __restrict__ WPSs,
                                              const float* __restrict__ ccv,
                                              float* __restrict__ OUT, int N) {
  __shared__ ushort Ah[64 * 64];
  __shared__ ushort Ax[64 * 64];
  const int tid = threadIdx.x;
  const int row0 = blockIdx.x * 64;
  {
    const int r = tid >> 2, q = tid & 3;
    const int grow = row0 + r;
    u16x8 lo = {0, 0, 0, 0, 0, 0, 0, 0}, hi = {0, 0, 0, 0, 0, 0, 0, 0};
    if (grow < N) {
      const u16x8* hp = (const u16x8*)&H2[(size_t)grow * 64 + q * 16];
      lo = hp[0];
      hi = hp[1];
    }
    char* base = (char*)Ah + r * 128;
    const int sw = (r & 7) << 4;
    *(u16x8*)(base + ((q * 32) ^ sw)) = lo;
    *(u16x8*)(base + ((q * 32 + 16) ^ sw)) = hi;
  }
  stageF32(Ax, X, row0, N, tid, 0.f);
  __syncthreads();
  const int l = tid & 63, w = tid >> 6;
  const int rowb = w * 16 + (l & 15);
  const int sw = (rowb & 7) << 4;
  const int kb = (l >> 4) << 4;
  const char* hb = (const char*)Ah + rowb * 128;
  const char* xb = (const char*)Ax + rowb * 128;
  const s16x8 ah0 = *(const s16x8*)(hb + (kb ^ sw));
  const s16x8 ah1 = *(const s16x8*)(hb + ((64 + kb) ^ sw));
  const s16x8 ax0 = *(const s16x8*)(xb + (kb ^ sw));
  const s16x8 ax1 = *(const s16x8*)(xb + ((64 + kb) ^ sw));
  const u16x8* wp3 = (const u16x8*)WP3s;
  const u16x8* wps = (const u16x8*)WPSs;
#pragma unroll 4
  for (int ct = 0; ct < 16; ++ct) {
    s16x8 b0 = (s16x8)wp3[(ct * 2 + 0) * 64 + l];
    s16x8 b1 = (s16x8)wp3[(ct * 2 + 1) * 64 + l];
    s16x8 s0 = (s16x8)wps[(ct * 2 + 0) * 64 + l];
    s16x8 s1 = (s16x8)wps[(ct * 2 + 1) * 64 + l];
    f32x4 acc = {0.f, 0.f, 0.f, 0.f};
    acc = mfma16(ah0, b0, acc);
    acc = mfma16(ah1, b1, acc);
    acc = mfma16(ax0, s0, acc);
    acc = mfma16(ax1, s1, acc);
    const int col = ct * 16 + (l & 15);
    const float cj = ccv[col];
#pragma unroll
    for (int reg = 0; reg < 4; ++reg) {
      const int grow = row0 + w * 16 + ((l >> 4) << 2) + reg;
      if (grow < N) OUT[(size_t)grow * 256 + col] = fmaxf(acc[reg] + cj, 0.f);
    }
  }
}

extern "C" void kernel_launch(void* const* d_in, const int* in_sizes, int n_in,
                              void* d_out, int out_size, void* d_ws, size_t ws_size,
                              hipStream_t stream) {
  const float* X  = (const float*)d_in[0];
  const int*   nbr = (const int*)d_in[1];
  const float* W1 = (const float*)d_in[2];
  const float* g1 = (const float*)d_in[3];
  const float* b1 = (const float*)d_in[4];
  const float* Wk = (const float*)d_in[5];
  const float* g2 = (const float*)d_in[6];
  const float* b2 = (const float*)d_in[7];
  const float* W3 = (const float*)d_in[8];
  const float* g3 = (const float*)d_in[9];
  const float* b3 = (const float*)d_in[10];
  const float* Ws = (const float*)d_in[11];
  const float* gs = (const float*)d_in[12];
  const float* bs = (const float*)d_in[13];
  float* out = (float*)d_out;
  float* ws  = (float*)d_ws;

  const int N = in_sizes[0] / 64;
  const float invN = 1.f / (float)N;

  // ws layout (float offsets)
  float* sum1S = ws + 0;     // [320] (0..63 = Y1, 64..319 = Ys)
  float* sq1S  = ws + 320;   // [320]
  float* sum2  = ws + 640;   // [64]
  float* sq2   = ws + 704;   // [64]
  float* sum3  = ws + 768;   // [256]
  float* sq3   = ws + 1024;  // [256]
  float* a1p = ws + 1280, *c1p = ws + 1344;
  float* aSp = ws + 1408, *cSp = ws + 1664;
  float* a2p = ws + 1920, *c2p = ws + 1984;
  float* a3p = ws + 2048, *c3p = ws + 2304;
  float* ccp = ws + 2560;                         // [256]
  ushort* WP1S = (ushort*)(ws + 2816);            // 20480 bf16
  ushort* WPkP = (ushort*)(ws + 13056);           // 36864 bf16
  ushort* WP3P = (ushort*)(ws + 31488);           // 16384 bf16
  ushort* WP3s = (ushort*)(ws + 39680);           // 16384 bf16
  ushort* WPSs = (ushort*)(ws + 47872);           // 16384 bf16
  ushort* H2b  = (ushort*)(ws + 56064);           // N*64 bf16 (~33 MB)
  // scratch in d_out (dead before kFinal writes)
  ushort* H1b = (ushort*)out;                     // N*64 bf16
  float*  Y2  = out + (size_t)N * 32;             // N*64 f32

  const int gb64 = (N + 63) / 64;

  kZero<<<5, 256, 0, stream>>>(ws, 1280);
  kPackW<<<288, 256, 0, stream>>>(W1, Ws, Wk, W3, WP1S, WPkP, WP3P);
  kStatsXW<<<gb64, 256, 0, stream>>>(X, WP1S, sum1S, sq1S, N);
  kFinStats<<<1, 64, 0, stream>>>(sum1S, sq1S, g1, b1, invN, a1p, c1p, 64);
  kFinStats<<<4, 64, 0, stream>>>(sum1S + 64, sq1S + 64, gs, bs, invN, aSp, cSp, 256);
  kGemm1<<<gb64, 256, 0, stream>>>(X, WP1S, a1p, c1p, H1b, N);
  kConv<<<gb64, 256, 0, stream>>>(H1b, nbr, WPkP, Y2, sum2, sq2, N);
  kFinStats<<<1, 64, 0, stream>>>(sum2, sq2, g2, b2, invN, a2p, c2p, 64);
  kH2S3<<<gb64, 256, 0, stream>>>(Y2, a2p, c2p, WP3P, H2b, sum3, sq3, N);
  kFinStats<<<4, 64, 0, stream>>>(sum3, sq3, g3, b3, invN, a3p, c3p, 256);
  kPackScaled<<<64, 256, 0, stream>>>(W3, Ws, a3p, aSp, c3p, cSp, WP3s, WPSs, ccp);
  kFinal<<<gb64, 256, 0, stream>>>(H2b, X, WP3s, WPSs, ccp, out, N);
}

// Round 6
// 473.592 us; speedup vs baseline: 1.0727x; 1.0626x over previous
//
#include <hip/hip_runtime.h>

typedef __attribute__((ext_vector_type(8))) short  s16x8;
typedef __attribute__((ext_vector_type(8))) unsigned short u16x8;
typedef __attribute__((ext_vector_type(4))) float  f32x4;

constexpr float BN_EPS = 1e-5f;
#define DEV_INLINE __device__ __forceinline__

DEV_INLINE ushort f2bf(float f) {
  unsigned int u = __float_as_uint(f);
  return (ushort)((u + 0x7FFFu + ((u >> 16) & 1u)) >> 16);
}
DEV_INLINE float bf2f(ushort b) { return __uint_as_float(((unsigned int)b) << 16); }

DEV_INLINE f32x4 mfma16(s16x8 a, s16x8 b, f32x4 c) {
  return __builtin_amdgcn_mfma_f32_16x16x32_bf16(a, b, c, 0, 0, 0);
}

// packed B-fragment index decode: r in [0,1024) -> (k, col16)
DEV_INLINE void decode_frag(int r, int& k, int& c16) {
  const int ks = r >> 9;
  const int l = (r >> 3) & 63;
  const int j = r & 7;
  k = ks * 32 + ((l >> 4) << 3) + j;
  c16 = l & 15;
}

// ---- pack W1|Ws (20 ct), Wk (9x4 ct), W3 (16 ct); zero stats region --------
__global__ void kPackW(const float* __restrict__ W1, const float* __restrict__ Ws,
                       const float* __restrict__ Wk, const float* __restrict__ W3,
                       ushort* __restrict__ WP1S, ushort* __restrict__ WPk,
                       ushort* __restrict__ WP3, float* __restrict__ statz) {
  int e = blockIdx.x * 256 + threadIdx.x;  // 73728 total
  if (e < 1280) statz[e] = 0.f;
  if (e < 20480) {
    int ct = e >> 10, r = e & 1023, k, c16;
    decode_frag(r, k, c16);
    float w = (ct < 4) ? W1[k * 64 + ct * 16 + c16] : Ws[k * 256 + (ct - 4) * 16 + c16];
    WP1S[e] = f2bf(w);
  } else if (e < 57344) {
    int e2 = e - 20480;
    int tap = e2 >> 12, r2 = e2 & 4095;
    int ct = r2 >> 10, k, c16;
    decode_frag(r2 & 1023, k, c16);
    WPk[e2] = f2bf(Wk[tap * 4096 + k * 64 + ct * 16 + c16]);
  } else {
    int e3 = e - 57344;
    int ct = e3 >> 10, k, c16;
    decode_frag(e3 & 1023, k, c16);
    WP3[e3] = f2bf(W3[k * 256 + ct * 16 + c16]);
  }
}

// ---- stage one 64-row f32 tile into swizzled bf16 LDS ----------------------
DEV_INLINE void stageF32(ushort* At, const float* __restrict__ src, int row0, int N,
                         int tid) {
  const int r = tid >> 2, q = tid & 3;
  const int grow = row0 + r;
  u16x8 lo = {0, 0, 0, 0, 0, 0, 0, 0}, hi = {0, 0, 0, 0, 0, 0, 0, 0};
  if (grow < N) {
    const float4* xp = reinterpret_cast<const float4*>(&src[(size_t)grow * 64 + q * 16]);
#pragma unroll
    for (int i = 0; i < 2; ++i) {
      float4 t = xp[i];
      lo[4 * i + 0] = f2bf(t.x); lo[4 * i + 1] = f2bf(t.y);
      lo[4 * i + 2] = f2bf(t.z); lo[4 * i + 3] = f2bf(t.w);
      float4 u = xp[i + 2];
      hi[4 * i + 0] = f2bf(u.x); hi[4 * i + 1] = f2bf(u.y);
      hi[4 * i + 2] = f2bf(u.z); hi[4 * i + 3] = f2bf(u.w);
    }
  }
  char* base = (char*)At + r * 128;
  const int sw = (r & 7) << 4;
  *(u16x8*)(base + ((q * 32) ^ sw)) = lo;
  *(u16x8*)(base + ((q * 32 + 16) ^ sw)) = hi;
}

// per-block BN finalize helper: channel j from global sums -> a,c
DEV_INLINE void bnFin(const float* sum, const float* sq, const float* g,
                      const float* b, float invN, int j, float* a_lds, float* c_lds) {
  float m = sum[j] * invN;
  float v = fmaxf(sq[j] * invN - m * m, 0.f);
  float al = g[j] * rsqrtf(v + BN_EPS);
  a_lds[j] = al;
  c_lds[j] = fmaf(-m, al, b[j]);
}

// ---- K1: colsum/colsq of X@[W1|Ws] (320 cols), no Y store ------------------
__global__ __launch_bounds__(256) void kStatsXW(const float* __restrict__ X,
                                                const ushort* __restrict__ WP,
                                                float* __restrict__ gsum,
                                                float* __restrict__ gsq, int N) {
  __shared__ ushort At[64 * 64];
  __shared__ float lsum[320], lsq[320];
  const int tid = threadIdx.x;
  const int row0 = blockIdx.x * 64;
  for (int i = tid; i < 320; i += 256) { lsum[i] = 0.f; lsq[i] = 0.f; }
  stageF32(At, X, row0, N, tid);
  __syncthreads();
  const int l = tid & 63, w = tid >> 6;
  const int rowb = w * 16 + (l & 15);
  const char* abase = (const char*)At + rowb * 128;
  const int sw = (rowb & 7) << 4;
  const int kb = (l >> 4) << 4;
  const s16x8 a0 = *(const s16x8*)(abase + (kb ^ sw));
  const s16x8 a1 = *(const s16x8*)(abase + ((64 + kb) ^ sw));
  const u16x8* wp = (const u16x8*)WP;
#pragma unroll 5
  for (int ct = 0; ct < 20; ++ct) {
    s16x8 b0 = (s16x8)wp[(ct * 2 + 0) * 64 + l];
    s16x8 b1 = (s16x8)wp[(ct * 2 + 1) * 64 + l];
    f32x4 acc = {0.f, 0.f, 0.f, 0.f};
    acc = mfma16(a0, b0, acc);
    acc = mfma16(a1, b1, acc);
    float sp = acc[0] + acc[1] + acc[2] + acc[3];
    float qp = acc[0] * acc[0] + acc[1] * acc[1] + acc[2] * acc[2] + acc[3] * acc[3];
    sp += __shfl_xor(sp, 16); sp += __shfl_xor(sp, 32);
    qp += __shfl_xor(qp, 16); qp += __shfl_xor(qp, 32);
    if ((l >> 4) == 0) {
      atomicAdd(&lsum[ct * 16 + (l & 15)], sp);
      atomicAdd(&lsq[ct * 16 + (l & 15)], qp);
    }
  }
  __syncthreads();
  for (int i = tid; i < 320; i += 256) {
    atomicAdd(&gsum[i], lsum[i]);
    atomicAdd(&gsq[i], lsq[i]);
  }
}

// ---- K2: h1 = relu(a1*(X@W1)+c1) -> bf16 (BN1 finalized in-block) ----------
__global__ __launch_bounds__(256) void kGemm1(const float* __restrict__ X,
                                              const ushort* __restrict__ WP,
                                              const float* __restrict__ sum1,
                                              const float* __restrict__ sq1,
                                              const float* __restrict__ g1,
                                              const float* __restrict__ b1,
                                              float invN, ushort* __restrict__ H1,
                                              int N) {
  __shared__ ushort At[64 * 64];
  __shared__ float a1s[64], c1s[64];
  const int tid = threadIdx.x;
  const int row0 = blockIdx.x * 64;
  if (tid < 64) bnFin(sum1, sq1, g1, b1, invN, tid, a1s, c1s);
  stageF32(At, X, row0, N, tid);
  __syncthreads();
  const int l = tid & 63, w = tid >> 6;
  const int rowb = w * 16 + (l & 15);
  const char* abase = (const char*)At + rowb * 128;
  const int sw = (rowb & 7) << 4;
  const int kb = (l >> 4) << 4;
  const s16x8 a0 = *(const s16x8*)(abase + (kb ^ sw));
  const s16x8 a1 = *(const s16x8*)(abase + ((64 + kb) ^ sw));
  const u16x8* wp = (const u16x8*)WP;
#pragma unroll
  for (int ct = 0; ct < 4; ++ct) {
    s16x8 b0 = (s16x8)wp[(ct * 2 + 0) * 64 + l];
    s16x8 b1v = (s16x8)wp[(ct * 2 + 1) * 64 + l];
    f32x4 acc = {0.f, 0.f, 0.f, 0.f};
    acc = mfma16(a0, b0, acc);
    acc = mfma16(a1, b1v, acc);
    const int col = ct * 16 + (l & 15);
    const float aj = a1s[col], cj = c1s[col];
#pragma unroll
    for (int reg = 0; reg < 4; ++reg) {
      const int grow = row0 + w * 16 + ((l >> 4) << 2) + reg;
      if (grow < N) H1[(size_t)grow * 64 + col] = f2bf(fmaxf(fmaf(acc[reg], aj, cj), 0.f));
    }
  }
}

// ---- K3: Y2 = sum_k gather_k(h1) @ Wk[k] (bf16 out) + BN2 col stats --------
// double-buffered LDS, register prefetch of tap k+1, ONE barrier per tap
__global__ __launch_bounds__(256) void kConv(const ushort* __restrict__ H1,
                                             const int* __restrict__ nbr,
                                             const ushort* __restrict__ WPk,
                                             ushort* __restrict__ Y2b,
                                             float* __restrict__ gsum,
                                             float* __restrict__ gsq, int N) {
  __shared__ ushort At[2][64 * 64];
  __shared__ int idx[576];
  __shared__ float lsum[64], lsq[64];
  const int tid = threadIdx.x;
  const int row0 = blockIdx.x * 64;
  if (tid < 64) { lsum[tid] = 0.f; lsq[tid] = 0.f; }
  for (int e = tid; e < 576; e += 256) {
    const int grow = row0 + e / 9;
    idx[e] = (grow < N) ? nbr[(size_t)row0 * 9 + e] : -1;
  }
  const int l = tid & 63, w = tid >> 6;
  const int rowb = w * 16 + (l & 15);
  const int swr = (rowb & 7) << 4;
  const int kb = (l >> 4) << 4;
  const int r = tid >> 2, q = tid & 3;
  const int sww = (r & 7) << 4;
  f32x4 acc[4];
#pragma unroll
  for (int ct = 0; ct < 4; ++ct) acc[ct] = {0.f, 0.f, 0.f, 0.f};
  const u16x8* wp = (const u16x8*)WPk;
  __syncthreads();  // idx ready
  // prefetch tap 0
  u16x8 lo = {0, 0, 0, 0, 0, 0, 0, 0}, hi = {0, 0, 0, 0, 0, 0, 0, 0};
  {
    const int src = idx[r * 9];
    if (src >= 0) {
      const u16x8* hp = (const u16x8*)&H1[(size_t)src * 64 + q * 16];
      lo = hp[0];
      hi = hp[1];
    }
  }
  for (int k = 0; k < 9; ++k) {
    // write prefetched tap into buf[k&1]
    char* wbase = (char*)At[k & 1] + r * 128;
    *(u16x8*)(wbase + ((q * 32) ^ sww)) = lo;
    *(u16x8*)(wbase + ((q * 32 + 16) ^ sww)) = hi;
    // prefetch tap k+1 (hidden under this tap's MFMAs)
    if (k < 8) {
      const int src = idx[r * 9 + k + 1];
      u16x8 z = {0, 0, 0, 0, 0, 0, 0, 0};
      lo = z; hi = z;
      if (src >= 0) {
        const u16x8* hp = (const u16x8*)&H1[(size_t)src * 64 + q * 16];
        lo = hp[0];
        hi = hp[1];
      }
    }
    __syncthreads();
    const char* abase = (const char*)At[k & 1] + rowb * 128;
    const s16x8 a0 = *(const s16x8*)(abase + (kb ^ swr));
    const s16x8 a1 = *(const s16x8*)(abase + ((64 + kb) ^ swr));
#pragma unroll
    for (int ct = 0; ct < 4; ++ct) {
      s16x8 b0 = (s16x8)wp[((size_t)((k * 4 + ct) * 2 + 0)) * 64 + l];
      s16x8 b1 = (s16x8)wp[((size_t)((k * 4 + ct) * 2 + 1)) * 64 + l];
      acc[ct] = mfma16(a0, b0, acc[ct]);
      acc[ct] = mfma16(a1, b1, acc[ct]);
    }
  }
#pragma unroll
  for (int ct = 0; ct < 4; ++ct) {
    const f32x4 v = acc[ct];
    const int col = ct * 16 + (l & 15);
#pragma unroll
    for (int reg = 0; reg < 4; ++reg) {
      const int grow = row0 + w * 16 + ((l >> 4) << 2) + reg;
      if (grow < N) Y2b[(size_t)grow * 64 + col] = f2bf(v[reg]);
    }
    float sp = v[0] + v[1] + v[2] + v[3];
    float qp = v[0] * v[0] + v[1] * v[1] + v[2] * v[2] + v[3] * v[3];
    sp += __shfl_xor(sp, 16); sp += __shfl_xor(sp, 32);
    qp += __shfl_xor(qp, 16); qp += __shfl_xor(qp, 32);
    if ((l >> 4) == 0) {
      atomicAdd(&lsum[col], sp);
      atomicAdd(&lsq[col], qp);
    }
  }
  __syncthreads();
  if (tid < 64) {
    atomicAdd(&gsum[tid], lsum[tid]);
    atomicAdd(&gsq[tid], lsq[tid]);
  }
}

// ---- stage h2 = relu(a2*Y2b+c2) into swizzled LDS (no global store) --------
DEV_INLINE void stageH2(ushort* At, const ushort* __restrict__ Y2b, int row0, int N,
                        int tid, const float* a2s, const float* c2s) {
  const int r = tid >> 2, q = tid & 3;
  const int grow = row0 + r;
  u16x8 lo = {0, 0, 0, 0, 0, 0, 0, 0}, hi = {0, 0, 0, 0, 0, 0, 0, 0};
  if (grow < N) {
    const u16x8* yp = (const u16x8*)&Y2b[(size_t)grow * 64 + q * 16];
    u16x8 ylo = yp[0], yhi = yp[1];
    const int cb = q * 16;
#pragma unroll
    for (int i = 0; i < 8; ++i) {
      lo[i] = f2bf(fmaxf(fmaf(bf2f(ylo[i]), a2s[cb + i], c2s[cb + i]), 0.f));
      hi[i] = f2bf(fmaxf(fmaf(bf2f(yhi[i]), a2s[cb + 8 + i], c2s[cb + 8 + i]), 0.f));
    }
  }
  char* base = (char*)At + r * 128;
  const int sw = (r & 7) << 4;
  *(u16x8*)(base + ((q * 32) ^ sw)) = lo;
  *(u16x8*)(base + ((q * 32 + 16) ^ sw)) = hi;
}

// ---- K4: BN3 stats of h2@W3 (h2 derived in-register, BN2 finalized in-block)
__global__ __launch_bounds__(256) void kH2S3(const ushort* __restrict__ Y2b,
                                             const float* __restrict__ sum2,
                                             const float* __restrict__ sq2,
                                             const float* __restrict__ g2,
                                             const float* __restrict__ b2,
                                             float invN,
                                             const ushort* __restrict__ WP3,
                                             float* __restrict__ gsum,
                                             float* __restrict__ gsq, int N) {
  __shared__ ushort At[64 * 64];
  __shared__ float lsum[256], lsq[256];
  __shared__ float a2s[64], c2s[64];
  const int tid = threadIdx.x;
  const int row0 = blockIdx.x * 64;
  for (int i = tid; i < 256; i += 256) { lsum[i] = 0.f; lsq[i] = 0.f; }
  if (tid < 64) bnFin(sum2, sq2, g2, b2, invN, tid, a2s, c2s);
  __syncthreads();
  stageH2(At, Y2b, row0, N, tid, a2s, c2s);
  __syncthreads();
  const int l = tid & 63, w = tid >> 6;
  const int rowb = w * 16 + (l & 15);
  const char* abase = (const char*)At + rowb * 128;
  const int sw = (rowb & 7) << 4;
  const int kb = (l >> 4) << 4;
  const s16x8 a0 = *(const s16x8*)(abase + (kb ^ sw));
  const s16x8 a1 = *(const s16x8*)(abase + ((64 + kb) ^ sw));
  const u16x8* wp = (const u16x8*)WP3;
#pragma unroll 4
  for (int ct = 0; ct < 16; ++ct) {
    s16x8 b0 = (s16x8)wp[(ct * 2 + 0) * 64 + l];
    s16x8 b1 = (s16x8)wp[(ct * 2 + 1) * 64 + l];
    f32x4 acc = {0.f, 0.f, 0.f, 0.f};
    acc = mfma16(a0, b0, acc);
    acc = mfma16(a1, b1, acc);
    float sp = acc[0] + acc[1] + acc[2] + acc[3];
    float qp = acc[0] * acc[0] + acc[1] * acc[1] + acc[2] * acc[2] + acc[3] * acc[3];
    sp += __shfl_xor(sp, 16); sp += __shfl_xor(sp, 32);
    qp += __shfl_xor(qp, 16); qp += __shfl_xor(qp, 32);
    if ((l >> 4) == 0) {
      atomicAdd(&lsum[ct * 16 + (l & 15)], sp);
      atomicAdd(&lsq[ct * 16 + (l & 15)], qp);
    }
  }
  __syncthreads();
  for (int i = tid; i < 256; i += 256) {
    atomicAdd(&gsum[i], lsum[i]);
    atomicAdd(&gsq[i], lsq[i]);
  }
}

// ---- K5: out = relu(a3*(h2@W3) + aS*(X@Ws) + c3+cS); all BN in-block -------
__global__ __launch_bounds__(256) void kFinal(
    const ushort* __restrict__ Y2b, const float* __restrict__ X,
    const ushort* __restrict__ WP3, const ushort* __restrict__ WP1S,
    const float* __restrict__ sum2, const float* __restrict__ sq2,
    const float* __restrict__ g2, const float* __restrict__ b2,
    const float* __restrict__ sum3, const float* __restrict__ sq3,
    const float* __restrict__ g3, const float* __restrict__ b3,
    const float* __restrict__ sumS, const float* __restrict__ sqS,
    const float* __restrict__ gs, const float* __restrict__ bs,
    float invN, float* __restrict__ OUT, int N) {
  __shared__ ushort Ah[64 * 64];
  __shared__ ushort Ax[64 * 64];
  __shared__ float a2s[64], c2s[64];
  __shared__ float a3s[256], c3s[256], aSs[256], cSs[256];
  const int tid = threadIdx.x;
  const int row0 = blockIdx.x * 64;
  if (tid < 64) bnFin(sum2, sq2, g2, b2, invN, tid, a2s, c2s);
  bnFin(sum3, sq3, g3, b3, invN, tid, a3s, c3s);
  bnFin(sumS, sqS, gs, bs, invN, tid, aSs, cSs);
  stageF32(Ax, X, row0, N, tid);
  __syncthreads();  // a2s ready before stageH2 reads it
  stageH2(Ah, Y2b, row0, N, tid, a2s, c2s);
  __syncthreads();
  const int l = tid & 63, w = tid >> 6;
  const int rowb = w * 16 + (l & 15);
  const int sw = (rowb & 7) << 4;
  const int kb = (l >> 4) << 4;
  const char* hb = (const char*)Ah + rowb * 128;
  const char* xb = (const char*)Ax + rowb * 128;
  const s16x8 ah0 = *(const s16x8*)(hb + (kb ^ sw));
  const s16x8 ah1 = *(const s16x8*)(hb + ((64 + kb) ^ sw));
  const s16x8 ax0 = *(const s16x8*)(xb + (kb ^ sw));
  const s16x8 ax1 = *(const s16x8*)(xb + ((64 + kb) ^ sw));
  const u16x8* wp3 = (const u16x8*)WP3;
  const u16x8* wps = (const u16x8*)WP1S + 8 * 64;  // skip W1's 4 ct
#pragma unroll 4
  for (int ct = 0; ct < 16; ++ct) {
    s16x8 b0 = (s16x8)wp3[(ct * 2 + 0) * 64 + l];
    s16x8 b1 = (s16x8)wp3[(ct * 2 + 1) * 64 + l];
    s16x8 s0 = (s16x8)wps[(ct * 2 + 0) * 64 + l];
    s16x8 s1 = (s16x8)wps[(ct * 2 + 1) * 64 + l];
    f32x4 acc3 = {0.f, 0.f, 0.f, 0.f};
    acc3 = mfma16(ah0, b0, acc3);
    acc3 = mfma16(ah1, b1, acc3);
    f32x4 accS = {0.f, 0.f, 0.f, 0.f};
    accS = mfma16(ax0, s0, accS);
    accS = mfma16(ax1, s1, accS);
    const int col = ct * 16 + (l & 15);
    const float a3j = a3s[col], aSj = aSs[col];
    const float ccj = c3s[col] + cSs[col];
#pragma unroll
    for (int reg = 0; reg < 4; ++reg) {
      const int grow = row0 + w * 16 + ((l >> 4) << 2) + reg;
      if (grow < N)
        OUT[(size_t)grow * 256 + col] =
            fmaxf(fmaf(acc3[reg], a3j, fmaf(accS[reg], aSj, ccj)), 0.f);
    }
  }
}

extern "C" void kernel_launch(void* const* d_in, const int* in_sizes, int n_in,
                              void* d_out, int out_size, void* d_ws, size_t ws_size,
                              hipStream_t stream) {
  const float* X  = (const float*)d_in[0];
  const int*   nbr = (const int*)d_in[1];
  const float* W1 = (const float*)d_in[2];
  const float* g1 = (const float*)d_in[3];
  const float* b1 = (const float*)d_in[4];
  const float* Wk = (const float*)d_in[5];
  const float* g2 = (const float*)d_in[6];
  const float* b2 = (const float*)d_in[7];
  const float* W3 = (const float*)d_in[8];
  const float* g3 = (const float*)d_in[9];
  const float* b3 = (const float*)d_in[10];
  const float* Ws = (const float*)d_in[11];
  const float* gs = (const float*)d_in[12];
  const float* bs = (const float*)d_in[13];
  float* out = (float*)d_out;
  float* ws  = (float*)d_ws;

  const int N = in_sizes[0] / 64;
  const float invN = 1.f / (float)N;

  // ws layout (float offsets)
  float* sum1S = ws + 0;     // [320] (0..63 = Y1, 64..319 = Ys)
  float* sq1S  = ws + 320;   // [320]
  float* sum2  = ws + 640;   // [64]
  float* sq2   = ws + 704;   // [64]
  float* sum3  = ws + 768;   // [256]
  float* sq3   = ws + 1024;  // [256]
  ushort* WP1S = (ushort*)(ws + 1280);   // 20480 bf16 -> floats [1280, 11520)
  ushort* WPkP = (ushort*)(ws + 11520);  // 36864 bf16 -> [11520, 29952)
  ushort* WP3P = (ushort*)(ws + 29952);  // 16384 bf16 -> [29952, 38144)
  ushort* Y2b  = (ushort*)(ws + 38144);  // N*64 bf16 (~33 MB)
  // scratch in d_out (read only by kConv, which completes before kFinal writes)
  ushort* H1b = (ushort*)out;            // N*64 bf16

  const int gb64 = (N + 63) / 64;

  kPackW<<<288, 256, 0, stream>>>(W1, Ws, Wk, W3, WP1S, WPkP, WP3P, ws);
  kStatsXW<<<gb64, 256, 0, stream>>>(X, WP1S, sum1S, sq1S, N);
  kGemm1<<<gb64, 256, 0, stream>>>(X, WP1S, sum1S, sq1S, g1, b1, invN, H1b, N);
  kConv<<<gb64, 256, 0, stream>>>(H1b, nbr, WPkP, Y2b, sum2, sq2, N);
  kH2S3<<<gb64, 256, 0, stream>>>(Y2b, sum2, sq2, g2, b2, invN, WP3P, sum3, sq3, N);
  kFinal<<<gb64, 256, 0, stream>>>(Y2b, X, WP3P, WP1S, sum2, sq2, g2, b2,
                                   sum3, sq3, g3, b3, sum1S + 64, sq1S + 64,
                                   gs, bs, invN, out, N);
}

// Round 7
// 382.503 us; speedup vs baseline: 1.3282x; 1.2381x over previous
//
#include <hip/hip_runtime.h>

typedef __attribute__((ext_vector_type(8))) short  s16x8;
typedef __attribute__((ext_vector_type(8))) unsigned short u16x8;
typedef __attribute__((ext_vector_type(4))) float  f32x4;

constexpr float BN_EPS = 1e-5f;
#define DEV_INLINE __device__ __forceinline__

DEV_INLINE ushort f2bf(float f) {
  unsigned int u = __float_as_uint(f);
  return (ushort)((u + 0x7FFFu + ((u >> 16) & 1u)) >> 16);
}
DEV_INLINE float bf2f(ushort b) { return __uint_as_float(((unsigned int)b) << 16); }

DEV_INLINE f32x4 mfma16(s16x8 a, s16x8 b, f32x4 c) {
  return __builtin_amdgcn_mfma_f32_16x16x32_bf16(a, b, c, 0, 0, 0);
}

// packed B-fragment index decode: r in [0,1024) -> (k, col16)
DEV_INLINE void decode_frag(int r, int& k, int& c16) {
  const int ks = r >> 9;
  const int l = (r >> 3) & 63;
  const int j = r & 7;
  k = ks * 32 + ((l >> 4) << 3) + j;
  c16 = l & 15;
}

// ---- pack W1|Ws (20 ct), Wk (9x4 ct), W3 (16 ct); zero stats region --------
__global__ void kPackW(const float* __restrict__ W1, const float* __restrict__ Ws,
                       const float* __restrict__ Wk, const float* __restrict__ W3,
                       ushort* __restrict__ WP1S, ushort* __restrict__ WPk,
                       ushort* __restrict__ WP3, float* __restrict__ statz) {
  int e = blockIdx.x * 256 + threadIdx.x;  // 73728 total
  if (e < 1280) statz[e] = 0.f;
  if (e < 20480) {
    int ct = e >> 10, r = e & 1023, k, c16;
    decode_frag(r, k, c16);
    float w = (ct < 4) ? W1[k * 64 + ct * 16 + c16] : Ws[k * 256 + (ct - 4) * 16 + c16];
    WP1S[e] = f2bf(w);
  } else if (e < 57344) {
    int e2 = e - 20480;
    int tap = e2 >> 12, r2 = e2 & 4095;
    int ct = r2 >> 10, k, c16;
    decode_frag(r2 & 1023, k, c16);
    WPk[e2] = f2bf(Wk[tap * 4096 + k * 64 + ct * 16 + c16]);
  } else {
    int e3 = e - 57344;
    int ct = e3 >> 10, k, c16;
    decode_frag(e3 & 1023, k, c16);
    WP3[e3] = f2bf(W3[k * 256 + ct * 16 + c16]);
  }
}

// ---- stage one 64-row bf16 tile into swizzled LDS --------------------------
DEV_INLINE void stageB16(ushort* At, const ushort* __restrict__ src, int row0,
                         int N, int tid) {
  const int r = tid >> 2, q = tid & 3;
  const int grow = row0 + r;
  u16x8 lo = {0, 0, 0, 0, 0, 0, 0, 0}, hi = {0, 0, 0, 0, 0, 0, 0, 0};
  if (grow < N) {
    const u16x8* hp = (const u16x8*)&src[(size_t)grow * 64 + q * 16];
    lo = hp[0];
    hi = hp[1];
  }
  char* base = (char*)At + r * 128;
  const int sw = (r & 7) << 4;
  *(u16x8*)(base + ((q * 32) ^ sw)) = lo;
  *(u16x8*)(base + ((q * 32 + 16) ^ sw)) = hi;
}

// per-block BN finalize helper: channel j from global sums -> a,c
DEV_INLINE void bnFin(const float* sum, const float* sq, const float* g,
                      const float* b, float invN, int j, float* a_lds, float* c_lds) {
  float m = sum[j] * invN;
  float v = fmaxf(sq[j] * invN - m * m, 0.f);
  float al = g[j] * rsqrtf(v + BN_EPS);
  a_lds[j] = al;
  c_lds[j] = fmaf(-m, al, b[j]);
}

// ---- K1: colsum/colsq of X@[W1|Ws] (320 cols); writes Xb (bf16); multi-tile
__global__ __launch_bounds__(256) void kStatsXW(const float* __restrict__ X,
                                                const ushort* __restrict__ WP,
                                                ushort* __restrict__ Xb,
                                                float* __restrict__ gsum,
                                                float* __restrict__ gsq,
                                                int N, int ntiles) {
  __shared__ ushort At[64 * 64];
  __shared__ float lsum[320], lsq[320];
  const int tid = threadIdx.x;
  for (int i = tid; i < 320; i += 256) { lsum[i] = 0.f; lsq[i] = 0.f; }
  const int l = tid & 63, w = tid >> 6;
  const int rowb = w * 16 + (l & 15);
  const char* abase = (const char*)At + rowb * 128;
  const int swr = (rowb & 7) << 4;
  const int kb = (l >> 4) << 4;
  const int r = tid >> 2, q = tid & 3;
  char* wbase = (char*)At + r * 128;
  const int sww = (r & 7) << 4;
  const u16x8* wp = (const u16x8*)WP;
  for (int t = blockIdx.x; t < ntiles; t += gridDim.x) {
    const int row0 = t * 64;
    const int grow = row0 + r;
    u16x8 lo = {0, 0, 0, 0, 0, 0, 0, 0}, hi = {0, 0, 0, 0, 0, 0, 0, 0};
    if (grow < N) {
      const float4* xp = reinterpret_cast<const float4*>(&X[(size_t)grow * 64 + q * 16]);
#pragma unroll
      for (int i = 0; i < 2; ++i) {
        float4 tv = xp[i];
        lo[4 * i + 0] = f2bf(tv.x); lo[4 * i + 1] = f2bf(tv.y);
        lo[4 * i + 2] = f2bf(tv.z); lo[4 * i + 3] = f2bf(tv.w);
        float4 uv = xp[i + 2];
        hi[4 * i + 0] = f2bf(uv.x); hi[4 * i + 1] = f2bf(uv.y);
        hi[4 * i + 2] = f2bf(uv.z); hi[4 * i + 3] = f2bf(uv.w);
      }
      *(u16x8*)&Xb[(size_t)grow * 64 + q * 16] = lo;
      *(u16x8*)&Xb[(size_t)grow * 64 + q * 16 + 8] = hi;
    }
    __syncthreads();  // prev tile's At reads done
    *(u16x8*)(wbase + ((q * 32) ^ sww)) = lo;
    *(u16x8*)(wbase + ((q * 32 + 16) ^ sww)) = hi;
    __syncthreads();
    const s16x8 a0 = *(const s16x8*)(abase + (kb ^ swr));
    const s16x8 a1 = *(const s16x8*)(abase + ((64 + kb) ^ swr));
#pragma unroll 5
    for (int ct = 0; ct < 20; ++ct) {
      s16x8 b0 = (s16x8)wp[(ct * 2 + 0) * 64 + l];
      s16x8 b1 = (s16x8)wp[(ct * 2 + 1) * 64 + l];
      f32x4 acc = {0.f, 0.f, 0.f, 0.f};
      acc = mfma16(a0, b0, acc);
      acc = mfma16(a1, b1, acc);
      float sp = acc[0] + acc[1] + acc[2] + acc[3];
      float qp = acc[0] * acc[0] + acc[1] * acc[1] + acc[2] * acc[2] + acc[3] * acc[3];
      sp += __shfl_xor(sp, 16); sp += __shfl_xor(sp, 32);
      qp += __shfl_xor(qp, 16); qp += __shfl_xor(qp, 32);
      if ((l >> 4) == 0) {
        atomicAdd(&lsum[ct * 16 + (l & 15)], sp);
        atomicAdd(&lsq[ct * 16 + (l & 15)], qp);
      }
    }
  }
  __syncthreads();
  for (int i = tid; i < 320; i += 256) {
    atomicAdd(&gsum[i], lsum[i]);
    atomicAdd(&gsq[i], lsq[i]);
  }
}

// ---- K2: h1 = relu(a1*(Xb@W1)+c1) -> bf16 (BN1 finalized in-block) ---------
__global__ __launch_bounds__(256) void kGemm1(const ushort* __restrict__ Xb,
                                              const ushort* __restrict__ WP,
                                              const float* __restrict__ sum1,
                                              const float* __restrict__ sq1,
                                              const float* __restrict__ g1,
                                              const float* __restrict__ b1,
                                              float invN, ushort* __restrict__ H1,
                                              int N) {
  __shared__ ushort At[64 * 64];
  __shared__ float a1s[64], c1s[64];
  const int tid = threadIdx.x;
  const int row0 = blockIdx.x * 64;
  if (tid < 64) bnFin(sum1, sq1, g1, b1, invN, tid, a1s, c1s);
  stageB16(At, Xb, row0, N, tid);
  __syncthreads();
  const int l = tid & 63, w = tid >> 6;
  const int rowb = w * 16 + (l & 15);
  const char* abase = (const char*)At + rowb * 128;
  const int sw = (rowb & 7) << 4;
  const int kb = (l >> 4) << 4;
  const s16x8 a0 = *(const s16x8*)(abase + (kb ^ sw));
  const s16x8 a1 = *(const s16x8*)(abase + ((64 + kb) ^ sw));
  const u16x8* wp = (const u16x8*)WP;
#pragma unroll
  for (int ct = 0; ct < 4; ++ct) {
    s16x8 b0 = (s16x8)wp[(ct * 2 + 0) * 64 + l];
    s16x8 b1v = (s16x8)wp[(ct * 2 + 1) * 64 + l];
    f32x4 acc = {0.f, 0.f, 0.f, 0.f};
    acc = mfma16(a0, b0, acc);
    acc = mfma16(a1, b1v, acc);
    const int col = ct * 16 + (l & 15);
    const float aj = a1s[col], cj = c1s[col];
#pragma unroll
    for (int reg = 0; reg < 4; ++reg) {
      const int grow = row0 + w * 16 + ((l >> 4) << 2) + reg;
      if (grow < N) H1[(size_t)grow * 64 + col] = f2bf(fmaxf(fmaf(acc[reg], aj, cj), 0.f));
    }
  }
}

// ---- K3: Y2 = sum_k gather_k(h1) @ Wk[k] + BN2 stats; multi-tile, dbuf -----
__global__ __launch_bounds__(256) void kConv(const ushort* __restrict__ H1,
                                             const int* __restrict__ nbr,
                                             const ushort* __restrict__ WPk,
                                             ushort* __restrict__ Y2b,
                                             float* __restrict__ gsum,
                                             float* __restrict__ gsq,
                                             int N, int ntiles) {
  __shared__ ushort At[2][64 * 64];
  __shared__ int idx[576];
  __shared__ float lsum[64], lsq[64];
  const int tid = threadIdx.x;
  if (tid < 64) { lsum[tid] = 0.f; lsq[tid] = 0.f; }
  const int l = tid & 63, w = tid >> 6;
  const int rowb = w * 16 + (l & 15);
  const int swr = (rowb & 7) << 4;
  const int kb = (l >> 4) << 4;
  const int r = tid >> 2, q = tid & 3;
  const int sww = (r & 7) << 4;
  const u16x8* wp = (const u16x8*)WPk;
  for (int t = blockIdx.x; t < ntiles; t += gridDim.x) {
    const int row0 = t * 64;
    __syncthreads();  // prev tile fully done with idx & At
    for (int e = tid; e < 576; e += 256) {
      const int gr = row0 + e / 9;
      idx[e] = (gr < N) ? nbr[(size_t)row0 * 9 + e] : -1;
    }
    __syncthreads();  // idx ready
    f32x4 acc[4];
#pragma unroll
    for (int ct = 0; ct < 4; ++ct) acc[ct] = {0.f, 0.f, 0.f, 0.f};
    u16x8 lo = {0, 0, 0, 0, 0, 0, 0, 0}, hi = {0, 0, 0, 0, 0, 0, 0, 0};
    {
      const int src = idx[r * 9];
      if (src >= 0) {
        const u16x8* hp = (const u16x8*)&H1[(size_t)src * 64 + q * 16];
        lo = hp[0];
        hi = hp[1];
      }
    }
    for (int k = 0; k < 9; ++k) {
      char* wbase = (char*)At[k & 1] + r * 128;
      *(u16x8*)(wbase + ((q * 32) ^ sww)) = lo;
      *(u16x8*)(wbase + ((q * 32 + 16) ^ sww)) = hi;
      if (k < 8) {
        const int src = idx[r * 9 + k + 1];
        u16x8 z = {0, 0, 0, 0, 0, 0, 0, 0};
        lo = z; hi = z;
        if (src >= 0) {
          const u16x8* hp = (const u16x8*)&H1[(size_t)src * 64 + q * 16];
          lo = hp[0];
          hi = hp[1];
        }
      }
      __syncthreads();
      const char* abase = (const char*)At[k & 1] + rowb * 128;
      const s16x8 a0 = *(const s16x8*)(abase + (kb ^ swr));
      const s16x8 a1 = *(const s16x8*)(abase + ((64 + kb) ^ swr));
#pragma unroll
      for (int ct = 0; ct < 4; ++ct) {
        s16x8 b0 = (s16x8)wp[((size_t)((k * 4 + ct) * 2 + 0)) * 64 + l];
        s16x8 b1 = (s16x8)wp[((size_t)((k * 4 + ct) * 2 + 1)) * 64 + l];
        acc[ct] = mfma16(a0, b0, acc[ct]);
        acc[ct] = mfma16(a1, b1, acc[ct]);
      }
    }
#pragma unroll
    for (int ct = 0; ct < 4; ++ct) {
      const f32x4 v = acc[ct];
      const int col = ct * 16 + (l & 15);
#pragma unroll
      for (int reg = 0; reg < 4; ++reg) {
        const int grow = row0 + w * 16 + ((l >> 4) << 2) + reg;
        if (grow < N) Y2b[(size_t)grow * 64 + col] = f2bf(v[reg]);
      }
      float sp = v[0] + v[1] + v[2] + v[3];
      float qp = v[0] * v[0] + v[1] * v[1] + v[2] * v[2] + v[3] * v[3];
      sp += __shfl_xor(sp, 16); sp += __shfl_xor(sp, 32);
      qp += __shfl_xor(qp, 16); qp += __shfl_xor(qp, 32);
      if ((l >> 4) == 0) {
        atomicAdd(&lsum[col], sp);
        atomicAdd(&lsq[col], qp);
      }
    }
  }
  __syncthreads();
  if (tid < 64) {
    atomicAdd(&gsum[tid], lsum[tid]);
    atomicAdd(&gsq[tid], lsq[tid]);
  }
}

// ---- stage h2 = relu(a2*Y2b+c2) into swizzled LDS (no global store) --------
DEV_INLINE void stageH2(ushort* At, const ushort* __restrict__ Y2b, int row0, int N,
                        int tid, const float* a2s, const float* c2s) {
  const int r = tid >> 2, q = tid & 3;
  const int grow = row0 + r;
  u16x8 lo = {0, 0, 0, 0, 0, 0, 0, 0}, hi = {0, 0, 0, 0, 0, 0, 0, 0};
  if (grow < N) {
    const u16x8* yp = (const u16x8*)&Y2b[(size_t)grow * 64 + q * 16];
    u16x8 ylo = yp[0], yhi = yp[1];
    const int cb = q * 16;
#pragma unroll
    for (int i = 0; i < 8; ++i) {
      lo[i] = f2bf(fmaxf(fmaf(bf2f(ylo[i]), a2s[cb + i], c2s[cb + i]), 0.f));
      hi[i] = f2bf(fmaxf(fmaf(bf2f(yhi[i]), a2s[cb + 8 + i], c2s[cb + 8 + i]), 0.f));
    }
  }
  char* base = (char*)At + r * 128;
  const int sw = (r & 7) << 4;
  *(u16x8*)(base + ((q * 32) ^ sw)) = lo;
  *(u16x8*)(base + ((q * 32 + 16) ^ sw)) = hi;
}

// ---- K4: BN3 stats of h2@W3 (h2 in-register); multi-tile -------------------
__global__ __launch_bounds__(256) void kH2S3(const ushort* __restrict__ Y2b,
                                             const float* __restrict__ sum2,
                                             const float* __restrict__ sq2,
                                             const float* __restrict__ g2,
                                             const float* __restrict__ b2,
                                             float invN,
                                             const ushort* __restrict__ WP3,
                                             float* __restrict__ gsum,
                                             float* __restrict__ gsq,
                                             int N, int ntiles) {
  __shared__ ushort At[64 * 64];
  __shared__ float lsum[256], lsq[256];
  __shared__ float a2s[64], c2s[64];
  const int tid = threadIdx.x;
  for (int i = tid; i < 256; i += 256) { lsum[i] = 0.f; lsq[i] = 0.f; }
  if (tid < 64) bnFin(sum2, sq2, g2, b2, invN, tid, a2s, c2s);
  __syncthreads();  // a2s/c2s + lsum ready
  const int l = tid & 63, w = tid >> 6;
  const int rowb = w * 16 + (l & 15);
  const char* abase = (const char*)At + rowb * 128;
  const int sw = (rowb & 7) << 4;
  const int kb = (l >> 4) << 4;
  const u16x8* wp = (const u16x8*)WP3;
  for (int t = blockIdx.x; t < ntiles; t += gridDim.x) {
    const int row0 = t * 64;
    stageH2(At, Y2b, row0, N, tid, a2s, c2s);
    __syncthreads();
    const s16x8 a0 = *(const s16x8*)(abase + (kb ^ sw));
    const s16x8 a1 = *(const s16x8*)(abase + ((64 + kb) ^ sw));
#pragma unroll 4
    for (int ct = 0; ct < 16; ++ct) {
      s16x8 b0 = (s16x8)wp[(ct * 2 + 0) * 64 + l];
      s16x8 b1 = (s16x8)wp[(ct * 2 + 1) * 64 + l];
      f32x4 acc = {0.f, 0.f, 0.f, 0.f};
      acc = mfma16(a0, b0, acc);
      acc = mfma16(a1, b1, acc);
      float sp = acc[0] + acc[1] + acc[2] + acc[3];
      float qp = acc[0] * acc[0] + acc[1] * acc[1] + acc[2] * acc[2] + acc[3] * acc[3];
      sp += __shfl_xor(sp, 16); sp += __shfl_xor(sp, 32);
      qp += __shfl_xor(qp, 16); qp += __shfl_xor(qp, 32);
      if ((l >> 4) == 0) {
        atomicAdd(&lsum[ct * 16 + (l & 15)], sp);
        atomicAdd(&lsq[ct * 16 + (l & 15)], qp);
      }
    }
    __syncthreads();  // At reads done before next tile's stage
  }
  for (int i = tid; i < 256; i += 256) {
    atomicAdd(&gsum[i], lsum[i]);
    atomicAdd(&gsq[i], lsq[i]);
  }
}

// ---- K5: out = relu(a3*(h2@W3) + aS*(Xb@Ws) + c3+cS); all BN in-block ------
__global__ __launch_bounds__(256) void kFinal(
    const ushort* __restrict__ Y2b, const ushort* __restrict__ Xb,
    const ushort* __restrict__ WP3, const ushort* __restrict__ WP1S,
    const float* __restrict__ sum2, const float* __restrict__ sq2,
    const float* __restrict__ g2, const float* __restrict__ b2,
    const float* __restrict__ sum3, const float* __restrict__ sq3,
    const float* __restrict__ g3, const float* __restrict__ b3,
    const float* __restrict__ sumS, const float* __restrict__ sqS,
    const float* __restrict__ gs, const float* __restrict__ bs,
    float invN, float* __restrict__ OUT, int N) {
  __shared__ ushort Ah[64 * 64];
  __shared__ ushort Ax[64 * 64];
  __shared__ float a2s[64], c2s[64];
  __shared__ float a3s[256], c3s[256], aSs[256], cSs[256];
  const int tid = threadIdx.x;
  const int row0 = blockIdx.x * 64;
  if (tid < 64) bnFin(sum2, sq2, g2, b2, invN, tid, a2s, c2s);
  bnFin(sum3, sq3, g3, b3, invN, tid, a3s, c3s);
  bnFin(sumS, sqS, gs, bs, invN, tid, aSs, cSs);
  stageB16(Ax, Xb, row0, N, tid);
  __syncthreads();  // a2s ready before stageH2 reads it
  stageH2(Ah, Y2b, row0, N, tid, a2s, c2s);
  __syncthreads();
  const int l = tid & 63, w = tid >> 6;
  const int rowb = w * 16 + (l & 15);
  const int sw = (rowb & 7) << 4;
  const int kb = (l >> 4) << 4;
  const char* hb = (const char*)Ah + rowb * 128;
  const char* xb = (const char*)Ax + rowb * 128;
  const s16x8 ah0 = *(const s16x8*)(hb + (kb ^ sw));
  const s16x8 ah1 = *(const s16x8*)(hb + ((64 + kb) ^ sw));
  const s16x8 ax0 = *(const s16x8*)(xb + (kb ^ sw));
  const s16x8 ax1 = *(const s16x8*)(xb + ((64 + kb) ^ sw));
  const u16x8* wp3 = (const u16x8*)WP3;
  const u16x8* wps = (const u16x8*)WP1S + 8 * 64;  // skip W1's 4 ct
#pragma unroll 4
  for (int ct = 0; ct < 16; ++ct) {
    s16x8 b0 = (s16x8)wp3[(ct * 2 + 0) * 64 + l];
    s16x8 b1 = (s16x8)wp3[(ct * 2 + 1) * 64 + l];
    s16x8 s0 = (s16x8)wps[(ct * 2 + 0) * 64 + l];
    s16x8 s1 = (s16x8)wps[(ct * 2 + 1) * 64 + l];
    f32x4 acc3 = {0.f, 0.f, 0.f, 0.f};
    acc3 = mfma16(ah0, b0, acc3);
    acc3 = mfma16(ah1, b1, acc3);
    f32x4 accS = {0.f, 0.f, 0.f, 0.f};
    accS = mfma16(ax0, s0, accS);
    accS = mfma16(ax1, s1, accS);
    const int col = ct * 16 + (l & 15);
    const float a3j = a3s[col], aSj = aSs[col];
    const float ccj = c3s[col] + cSs[col];
#pragma unroll
    for (int reg = 0; reg < 4; ++reg) {
      const int grow = row0 + w * 16 + ((l >> 4) << 2) + reg;
      if (grow < N) {
        const float ov = fmaxf(fmaf(acc3[reg], a3j, fmaf(accS[reg], aSj, ccj)), 0.f);
        __builtin_nontemporal_store(ov, &OUT[(size_t)grow * 256 + col]);
      }
    }
  }
}

extern "C" void kernel_launch(void* const* d_in, const int* in_sizes, int n_in,
                              void* d_out, int out_size, void* d_ws, size_t ws_size,
                              hipStream_t stream) {
  const float* X  = (const float*)d_in[0];
  const int*   nbr = (const int*)d_in[1];
  const float* W1 = (const float*)d_in[2];
  const float* g1 = (const float*)d_in[3];
  const float* b1 = (const float*)d_in[4];
  const float* Wk = (const float*)d_in[5];
  const float* g2 = (const float*)d_in[6];
  const float* b2 = (const float*)d_in[7];
  const float* W3 = (const float*)d_in[8];
  const float* g3 = (const float*)d_in[9];
  const float* b3 = (const float*)d_in[10];
  const float* Ws = (const float*)d_in[11];
  const float* gs = (const float*)d_in[12];
  const float* bs = (const float*)d_in[13];
  float* out = (float*)d_out;
  float* ws  = (float*)d_ws;

  const int N = in_sizes[0] / 64;
  const float invN = 1.f / (float)N;
  const int ntiles = (N + 63) / 64;

  // ws layout (float offsets)
  float* sum1S = ws + 0;     // [320]
  float* sq1S  = ws + 320;   // [320]
  float* sum2  = ws + 640;   // [64]
  float* sq2   = ws + 704;   // [64]
  float* sum3  = ws + 768;   // [256]
  float* sq3   = ws + 1024;  // [256]
  ushort* WP1S = (ushort*)(ws + 1280);   // 20480 bf16
  ushort* WPkP = (ushort*)(ws + 11520);  // 36864 bf16
  ushort* WP3P = (ushort*)(ws + 29952);  // 16384 bf16
  ushort* Xb   = (ushort*)(ws + 38144);                      // N*64 bf16
  ushort* Y2b  = (ushort*)(ws + 38144 + (size_t)N * 32);     // N*64 bf16
  ushort* H1b  = (ushort*)(ws + 38144 + (size_t)N * 64);     // N*64 bf16

  kPackW<<<288, 256, 0, stream>>>(W1, Ws, Wk, W3, WP1S, WPkP, WP3P, ws);
  kStatsXW<<<508, 256, 0, stream>>>(X, WP1S, Xb, sum1S, sq1S, N, ntiles);
  kGemm1<<<ntiles, 256, 0, stream>>>(Xb, WP1S, sum1S, sq1S, g1, b1, invN, H1b, N);
  kConv<<<1016, 256, 0, stream>>>(H1b, nbr, WPkP, Y2b, sum2, sq2, N, ntiles);
  kH2S3<<<508, 256, 0, stream>>>(Y2b, sum2, sq2, g2, b2, invN, WP3P, sum3, sq3, N, ntiles);
  kFinal<<<ntiles, 256, 0, stream>>>(Y2b, Xb, WP3P, WP1S, sum2, sq2, g2, b2,
                                     sum3, sq3, g3, b3, sum1S + 64, sq1S + 64,
                                     gs, bs, invN, out, N);
}

// Round 8
// 351.954 us; speedup vs baseline: 1.4435x; 1.0868x over previous
//
#include <hip/hip_runtime.h>

typedef __attribute__((ext_vector_type(8))) short  s16x8;
typedef __attribute__((ext_vector_type(8))) unsigned short u16x8;
typedef __attribute__((ext_vector_type(4))) float  f32x4;

constexpr float BN_EPS = 1e-5f;
#define DEV_INLINE __device__ __forceinline__

DEV_INLINE ushort f2bf(float f) {
  unsigned int u = __float_as_uint(f);
  return (ushort)((u + 0x7FFFu + ((u >> 16) & 1u)) >> 16);
}
DEV_INLINE float bf2f(ushort b) { return __uint_as_float(((unsigned int)b) << 16); }

DEV_INLINE f32x4 mfma16(s16x8 a, s16x8 b, f32x4 c) {
  return __builtin_amdgcn_mfma_f32_16x16x32_bf16(a, b, c, 0, 0, 0);
}

// packed B-fragment index decode: r in [0,1024) -> (k, col16)
DEV_INLINE void decode_frag(int r, int& k, int& c16) {
  const int ks = r >> 9;
  const int l = (r >> 3) & 63;
  const int j = r & 7;
  k = ks * 32 + ((l >> 4) << 3) + j;
  c16 = l & 15;
}

// ---- pack W1|Ws (20 ct), Wk (9x4 ct), W3 (16 ct); zero stats region --------
__global__ void kPackW(const float* __restrict__ W1, const float* __restrict__ Ws,
                       const float* __restrict__ Wk, const float* __restrict__ W3,
                       ushort* __restrict__ WP1S, ushort* __restrict__ WPk,
                       ushort* __restrict__ WP3, float* __restrict__ statz) {
  int e = blockIdx.x * 256 + threadIdx.x;  // 73728 total
  if (e < 1280) statz[e] = 0.f;
  if (e < 20480) {
    int ct = e >> 10, r = e & 1023, k, c16;
    decode_frag(r, k, c16);
    float w = (ct < 4) ? W1[k * 64 + ct * 16 + c16] : Ws[k * 256 + (ct - 4) * 16 + c16];
    WP1S[e] = f2bf(w);
  } else if (e < 57344) {
    int e2 = e - 20480;
    int tap = e2 >> 12, r2 = e2 & 4095;
    int ct = r2 >> 10, k, c16;
    decode_frag(r2 & 1023, k, c16);
    WPk[e2] = f2bf(Wk[tap * 4096 + k * 64 + ct * 16 + c16]);
  } else {
    int e3 = e - 57344;
    int ct = e3 >> 10, k, c16;
    decode_frag(e3 & 1023, k, c16);
    WP3[e3] = f2bf(W3[k * 256 + ct * 16 + c16]);
  }
}

// ---- stage one 64-row bf16 tile into swizzled LDS --------------------------
DEV_INLINE void stageB16(ushort* At, const ushort* __restrict__ src, int row0,
                         int N, int tid) {
  const int r = tid >> 2, q = tid & 3;
  const int grow = row0 + r;
  u16x8 lo = {0, 0, 0, 0, 0, 0, 0, 0}, hi = {0, 0, 0, 0, 0, 0, 0, 0};
  if (grow < N) {
    const u16x8* hp = (const u16x8*)&src[(size_t)grow * 64 + q * 16];
    lo = hp[0];
    hi = hp[1];
  }
  char* base = (char*)At + r * 128;
  const int sw = (r & 7) << 4;
  *(u16x8*)(base + ((q * 32) ^ sw)) = lo;
  *(u16x8*)(base + ((q * 32 + 16) ^ sw)) = hi;
}

// per-block BN finalize helper: channel j from global sums -> a,c
DEV_INLINE void bnFin(const float* sum, const float* sq, const float* g,
                      const float* b, float invN, int j, float* a_lds, float* c_lds) {
  float m = sum[j] * invN;
  float v = fmaxf(sq[j] * invN - m * m, 0.f);
  float al = g[j] * rsqrtf(v + BN_EPS);
  a_lds[j] = al;
  c_lds[j] = fmaf(-m, al, b[j]);
}

// ---- K1: colsum/colsq of X@[W1|Ws] (320 cols); writes Xb (bf16); multi-tile
__global__ __launch_bounds__(256) void kStatsXW(const float* __restrict__ X,
                                                const ushort* __restrict__ WP,
                                                ushort* __restrict__ Xb,
                                                float* __restrict__ gsum,
                                                float* __restrict__ gsq,
                                                int N, int ntiles) {
  __shared__ ushort At[64 * 64];
  __shared__ float lsum[320], lsq[320];
  const int tid = threadIdx.x;
  for (int i = tid; i < 320; i += 256) { lsum[i] = 0.f; lsq[i] = 0.f; }
  const int l = tid & 63, w = tid >> 6;
  const int rowb = w * 16 + (l & 15);
  const char* abase = (const char*)At + rowb * 128;
  const int swr = (rowb & 7) << 4;
  const int kb = (l >> 4) << 4;
  const int r = tid >> 2, q = tid & 3;
  char* wbase = (char*)At + r * 128;
  const int sww = (r & 7) << 4;
  const u16x8* wp = (const u16x8*)WP;
  for (int t = blockIdx.x; t < ntiles; t += gridDim.x) {
    const int row0 = t * 64;
    const int grow = row0 + r;
    u16x8 lo = {0, 0, 0, 0, 0, 0, 0, 0}, hi = {0, 0, 0, 0, 0, 0, 0, 0};
    if (grow < N) {
      const float4* xp = reinterpret_cast<const float4*>(&X[(size_t)grow * 64 + q * 16]);
#pragma unroll
      for (int i = 0; i < 2; ++i) {
        float4 tv = xp[i];
        lo[4 * i + 0] = f2bf(tv.x); lo[4 * i + 1] = f2bf(tv.y);
        lo[4 * i + 2] = f2bf(tv.z); lo[4 * i + 3] = f2bf(tv.w);
        float4 uv = xp[i + 2];
        hi[4 * i + 0] = f2bf(uv.x); hi[4 * i + 1] = f2bf(uv.y);
        hi[4 * i + 2] = f2bf(uv.z); hi[4 * i + 3] = f2bf(uv.w);
      }
      *(u16x8*)&Xb[(size_t)grow * 64 + q * 16] = lo;
      *(u16x8*)&Xb[(size_t)grow * 64 + q * 16 + 8] = hi;
    }
    __syncthreads();  // prev tile's At reads done
    *(u16x8*)(wbase + ((q * 32) ^ sww)) = lo;
    *(u16x8*)(wbase + ((q * 32 + 16) ^ sww)) = hi;
    __syncthreads();
    const s16x8 a0 = *(const s16x8*)(abase + (kb ^ swr));
    const s16x8 a1 = *(const s16x8*)(abase + ((64 + kb) ^ swr));
#pragma unroll 5
    for (int ct = 0; ct < 20; ++ct) {
      s16x8 b0 = (s16x8)wp[(ct * 2 + 0) * 64 + l];
      s16x8 b1 = (s16x8)wp[(ct * 2 + 1) * 64 + l];
      f32x4 acc = {0.f, 0.f, 0.f, 0.f};
      acc = mfma16(a0, b0, acc);
      acc = mfma16(a1, b1, acc);
      float sp = acc[0] + acc[1] + acc[2] + acc[3];
      float qp = acc[0] * acc[0] + acc[1] * acc[1] + acc[2] * acc[2] + acc[3] * acc[3];
      sp += __shfl_xor(sp, 16); sp += __shfl_xor(sp, 32);
      qp += __shfl_xor(qp, 16); qp += __shfl_xor(qp, 32);
      if ((l >> 4) == 0) {
        atomicAdd(&lsum[ct * 16 + (l & 15)], sp);
        atomicAdd(&lsq[ct * 16 + (l & 15)], qp);
      }
    }
  }
  __syncthreads();
  for (int i = tid; i < 320; i += 256) {
    atomicAdd(&gsum[i], lsum[i]);
    atomicAdd(&gsq[i], lsq[i]);
  }
}

// ---- K2: h1 = relu(a1*(Xb@W1)+c1) -> bf16 (BN1 finalized in-block) ---------
__global__ __launch_bounds__(256) void kGemm1(const ushort* __restrict__ Xb,
                                              const ushort* __restrict__ WP,
                                              const float* __restrict__ sum1,
                                              const float* __restrict__ sq1,
                                              const float* __restrict__ g1,
                                              const float* __restrict__ b1,
                                              float invN, ushort* __restrict__ H1,
                                              int N) {
  __shared__ ushort At[64 * 64];
  __shared__ float a1s[64], c1s[64];
  const int tid = threadIdx.x;
  const int row0 = blockIdx.x * 64;
  if (tid < 64) bnFin(sum1, sq1, g1, b1, invN, tid, a1s, c1s);
  stageB16(At, Xb, row0, N, tid);
  __syncthreads();
  const int l = tid & 63, w = tid >> 6;
  const int rowb = w * 16 + (l & 15);
  const char* abase = (const char*)At + rowb * 128;
  const int sw = (rowb & 7) << 4;
  const int kb = (l >> 4) << 4;
  const s16x8 a0 = *(const s16x8*)(abase + (kb ^ sw));
  const s16x8 a1 = *(const s16x8*)(abase + ((64 + kb) ^ sw));
  const u16x8* wp = (const u16x8*)WP;
#pragma unroll
  for (int ct = 0; ct < 4; ++ct) {
    s16x8 b0 = (s16x8)wp[(ct * 2 + 0) * 64 + l];
    s16x8 b1v = (s16x8)wp[(ct * 2 + 1) * 64 + l];
    f32x4 acc = {0.f, 0.f, 0.f, 0.f};
    acc = mfma16(a0, b0, acc);
    acc = mfma16(a1, b1v, acc);
    const int col = ct * 16 + (l & 15);
    const float aj = a1s[col], cj = c1s[col];
#pragma unroll
    for (int reg = 0; reg < 4; ++reg) {
      const int grow = row0 + w * 16 + ((l >> 4) << 2) + reg;
      if (grow < N) H1[(size_t)grow * 64 + col] = f2bf(fmaxf(fmaf(acc[reg], aj, cj), 0.f));
    }
  }
}

// ---- K3: Y2 = sum_k gather_k(h1) @ Wk[k] + BN2 stats -----------------------
// ALL 9 taps gathered upfront (loads fully overlapped), 9 LDS tap buffers,
// no barriers between taps; contiguous tile chunks for L2 halo locality.
__global__ __launch_bounds__(256) void kConv(const ushort* __restrict__ H1,
                                             const int* __restrict__ nbr,
                                             const ushort* __restrict__ WPk,
                                             ushort* __restrict__ Y2b,
                                             float* __restrict__ gsum,
                                             float* __restrict__ gsq,
                                             int N, int ntiles, int tpb) {
  __shared__ ushort At[9][64 * 64];
  __shared__ int idx[576];
  __shared__ float lsum[64], lsq[64];
  const int tid = threadIdx.x;
  if (tid < 64) { lsum[tid] = 0.f; lsq[tid] = 0.f; }
  const int l = tid & 63, w = tid >> 6;
  const int rowb = w * 16 + (l & 15);
  const int swr = (rowb & 7) << 4;
  const int kb = (l >> 4) << 4;
  const int r = tid >> 2, q = tid & 3;
  const int sww = (r & 7) << 4;
  const u16x8* wp = (const u16x8*)WPk;
  const int t0 = blockIdx.x * tpb;
  const int t1 = min(t0 + tpb, ntiles);
  for (int t = t0; t < t1; ++t) {
    const int row0 = t * 64;
    __syncthreads();  // prev tile fully consumed
    for (int e = tid; e < 576; e += 256) {
      const int gr = row0 + e / 9;
      idx[e] = (gr < N) ? nbr[(size_t)row0 * 9 + e] : -1;
    }
    __syncthreads();  // idx ready
    // gather all 9 taps into registers — all 18 loads in flight at once
    u16x8 glo[9], ghi[9];
#pragma unroll
    for (int k = 0; k < 9; ++k) {
      const int src = idx[r * 9 + k];
      u16x8 z = {0, 0, 0, 0, 0, 0, 0, 0};
      glo[k] = z;
      ghi[k] = z;
      if (src >= 0) {
        const u16x8* hp = (const u16x8*)&H1[(size_t)src * 64 + q * 16];
        glo[k] = hp[0];
        ghi[k] = hp[1];
      }
    }
#pragma unroll
    for (int k = 0; k < 9; ++k) {
      char* wbase = (char*)At[k] + r * 128;
      *(u16x8*)(wbase + ((q * 32) ^ sww)) = glo[k];
      *(u16x8*)(wbase + ((q * 32 + 16) ^ sww)) = ghi[k];
    }
    __syncthreads();  // all taps staged
    f32x4 acc[4];
#pragma unroll
    for (int ct = 0; ct < 4; ++ct) acc[ct] = {0.f, 0.f, 0.f, 0.f};
#pragma unroll
    for (int k = 0; k < 9; ++k) {
      const char* abase = (const char*)At[k] + rowb * 128;
      const s16x8 a0 = *(const s16x8*)(abase + (kb ^ swr));
      const s16x8 a1 = *(const s16x8*)(abase + ((64 + kb) ^ swr));
#pragma unroll
      for (int ct = 0; ct < 4; ++ct) {
        s16x8 b0 = (s16x8)wp[(size_t)((k * 4 + ct) * 2 + 0) * 64 + l];
        s16x8 b1 = (s16x8)wp[(size_t)((k * 4 + ct) * 2 + 1) * 64 + l];
        acc[ct] = mfma16(a0, b0, acc[ct]);
        acc[ct] = mfma16(a1, b1, acc[ct]);
      }
    }
#pragma unroll
    for (int ct = 0; ct < 4; ++ct) {
      const f32x4 v = acc[ct];
      const int col = ct * 16 + (l & 15);
#pragma unroll
      for (int reg = 0; reg < 4; ++reg) {
        const int grow = row0 + w * 16 + ((l >> 4) << 2) + reg;
        if (grow < N) Y2b[(size_t)grow * 64 + col] = f2bf(v[reg]);
      }
      float sp = v[0] + v[1] + v[2] + v[3];
      float qp = v[0] * v[0] + v[1] * v[1] + v[2] * v[2] + v[3] * v[3];
      sp += __shfl_xor(sp, 16); sp += __shfl_xor(sp, 32);
      qp += __shfl_xor(qp, 16); qp += __shfl_xor(qp, 32);
      if ((l >> 4) == 0) {
        atomicAdd(&lsum[col], sp);
        atomicAdd(&lsq[col], qp);
      }
    }
  }
  __syncthreads();
  if (tid < 64) {
    atomicAdd(&gsum[tid], lsum[tid]);
    atomicAdd(&gsq[tid], lsq[tid]);
  }
}

// ---- stage h2 = relu(a2*Y2b+c2) into swizzled LDS (no global store) --------
DEV_INLINE void stageH2(ushort* At, const ushort* __restrict__ Y2b, int row0, int N,
                        int tid, const float* a2s, const float* c2s) {
  const int r = tid >> 2, q = tid & 3;
  const int grow = row0 + r;
  u16x8 lo = {0, 0, 0, 0, 0, 0, 0, 0}, hi = {0, 0, 0, 0, 0, 0, 0, 0};
  if (grow < N) {
    const u16x8* yp = (const u16x8*)&Y2b[(size_t)grow * 64 + q * 16];
    u16x8 ylo = yp[0], yhi = yp[1];
    const int cb = q * 16;
#pragma unroll
    for (int i = 0; i < 8; ++i) {
      lo[i] = f2bf(fmaxf(fmaf(bf2f(ylo[i]), a2s[cb + i], c2s[cb + i]), 0.f));
      hi[i] = f2bf(fmaxf(fmaf(bf2f(yhi[i]), a2s[cb + 8 + i], c2s[cb + 8 + i]), 0.f));
    }
  }
  char* base = (char*)At + r * 128;
  const int sw = (r & 7) << 4;
  *(u16x8*)(base + ((q * 32) ^ sw)) = lo;
  *(u16x8*)(base + ((q * 32 + 16) ^ sw)) = hi;
}

// ---- K4: BN3 stats of h2@W3 (h2 in-register); multi-tile -------------------
__global__ __launch_bounds__(256) void kH2S3(const ushort* __restrict__ Y2b,
                                             const float* __restrict__ sum2,
                                             const float* __restrict__ sq2,
                                             const float* __restrict__ g2,
                                             const float* __restrict__ b2,
                                             float invN,
                                             const ushort* __restrict__ WP3,
                                             float* __restrict__ gsum,
                                             float* __restrict__ gsq,
                                             int N, int ntiles) {
  __shared__ ushort At[64 * 64];
  __shared__ float lsum[256], lsq[256];
  __shared__ float a2s[64], c2s[64];
  const int tid = threadIdx.x;
  for (int i = tid; i < 256; i += 256) { lsum[i] = 0.f; lsq[i] = 0.f; }
  if (tid < 64) bnFin(sum2, sq2, g2, b2, invN, tid, a2s, c2s);
  __syncthreads();  // a2s/c2s + lsum ready
  const int l = tid & 63, w = tid >> 6;
  const int rowb = w * 16 + (l & 15);
  const char* abase = (const char*)At + rowb * 128;
  const int sw = (rowb & 7) << 4;
  const int kb = (l >> 4) << 4;
  const u16x8* wp = (const u16x8*)WP3;
  for (int t = blockIdx.x; t < ntiles; t += gridDim.x) {
    const int row0 = t * 64;
    stageH2(At, Y2b, row0, N, tid, a2s, c2s);
    __syncthreads();
    const s16x8 a0 = *(const s16x8*)(abase + (kb ^ sw));
    const s16x8 a1 = *(const s16x8*)(abase + ((64 + kb) ^ sw));
#pragma unroll 4
    for (int ct = 0; ct < 16; ++ct) {
      s16x8 b0 = (s16x8)wp[(ct * 2 + 0) * 64 + l];
      s16x8 b1 = (s16x8)wp[(ct * 2 + 1) * 64 + l];
      f32x4 acc = {0.f, 0.f, 0.f, 0.f};
      acc = mfma16(a0, b0, acc);
      acc = mfma16(a1, b1, acc);
      float sp = acc[0] + acc[1] + acc[2] + acc[3];
      float qp = acc[0] * acc[0] + acc[1] * acc[1] + acc[2] * acc[2] + acc[3] * acc[3];
      sp += __shfl_xor(sp, 16); sp += __shfl_xor(sp, 32);
      qp += __shfl_xor(qp, 16); qp += __shfl_xor(qp, 32);
      if ((l >> 4) == 0) {
        atomicAdd(&lsum[ct * 16 + (l & 15)], sp);
        atomicAdd(&lsq[ct * 16 + (l & 15)], qp);
      }
    }
    __syncthreads();  // At reads done before next tile's stage
  }
  for (int i = tid; i < 256; i += 256) {
    atomicAdd(&gsum[i], lsum[i]);
    atomicAdd(&gsq[i], lsq[i]);
  }
}

// ---- K5: out = relu(a3*(h2@W3) + aS*(Xb@Ws) + c3+cS); all BN in-block ------
__global__ __launch_bounds__(256) void kFinal(
    const ushort* __restrict__ Y2b, const ushort* __restrict__ Xb,
    const ushort* __restrict__ WP3, const ushort* __restrict__ WP1S,
    const float* __restrict__ sum2, const float* __restrict__ sq2,
    const float* __restrict__ g2, const float* __restrict__ b2,
    const float* __restrict__ sum3, const float* __restrict__ sq3,
    const float* __restrict__ g3, const float* __restrict__ b3,
    const float* __restrict__ sumS, const float* __restrict__ sqS,
    const float* __restrict__ gs, const float* __restrict__ bs,
    float invN, float* __restrict__ OUT, int N) {
  __shared__ ushort Ah[64 * 64];
  __shared__ ushort Ax[64 * 64];
  __shared__ float a2s[64], c2s[64];
  __shared__ float a3s[256], c3s[256], aSs[256], cSs[256];
  const int tid = threadIdx.x;
  const int row0 = blockIdx.x * 64;
  if (tid < 64) bnFin(sum2, sq2, g2, b2, invN, tid, a2s, c2s);
  bnFin(sum3, sq3, g3, b3, invN, tid, a3s, c3s);
  bnFin(sumS, sqS, gs, bs, invN, tid, aSs, cSs);
  stageB16(Ax, Xb, row0, N, tid);
  __syncthreads();  // a2s ready before stageH2 reads it
  stageH2(Ah, Y2b, row0, N, tid, a2s, c2s);
  __syncthreads();
  const int l = tid & 63, w = tid >> 6;
  const int rowb = w * 16 + (l & 15);
  const int sw = (rowb & 7) << 4;
  const int kb = (l >> 4) << 4;
  const char* hb = (const char*)Ah + rowb * 128;
  const char* xb = (const char*)Ax + rowb * 128;
  const s16x8 ah0 = *(const s16x8*)(hb + (kb ^ sw));
  const s16x8 ah1 = *(const s16x8*)(hb + ((64 + kb) ^ sw));
  const s16x8 ax0 = *(const s16x8*)(xb + (kb ^ sw));
  const s16x8 ax1 = *(const s16x8*)(xb + ((64 + kb) ^ sw));
  const u16x8* wp3 = (const u16x8*)WP3;
  const u16x8* wps = (const u16x8*)WP1S + 8 * 64;  // skip W1's 4 ct
#pragma unroll 4
  for (int ct = 0; ct < 16; ++ct) {
    s16x8 b0 = (s16x8)wp3[(ct * 2 + 0) * 64 + l];
    s16x8 b1 = (s16x8)wp3[(ct * 2 + 1) * 64 + l];
    s16x8 s0 = (s16x8)wps[(ct * 2 + 0) * 64 + l];
    s16x8 s1 = (s16x8)wps[(ct * 2 + 1) * 64 + l];
    f32x4 acc3 = {0.f, 0.f, 0.f, 0.f};
    acc3 = mfma16(ah0, b0, acc3);
    acc3 = mfma16(ah1, b1, acc3);
    f32x4 accS = {0.f, 0.f, 0.f, 0.f};
    accS = mfma16(ax0, s0, accS);
    accS = mfma16(ax1, s1, accS);
    const int col = ct * 16 + (l & 15);
    const float a3j = a3s[col], aSj = aSs[col];
    const float ccj = c3s[col] + cSs[col];
#pragma unroll
    for (int reg = 0; reg < 4; ++reg) {
      const int grow = row0 + w * 16 + ((l >> 4) << 2) + reg;
      if (grow < N) {
        const float ov = fmaxf(fmaf(acc3[reg], a3j, fmaf(accS[reg], aSj, ccj)), 0.f);
        __builtin_nontemporal_store(ov, &OUT[(size_t)grow * 256 + col]);
      }
    }
  }
}

extern "C" void kernel_launch(void* const* d_in, const int* in_sizes, int n_in,
                              void* d_out, int out_size, void* d_ws, size_t ws_size,
                              hipStream_t stream) {
  const float* X  = (const float*)d_in[0];
  const int*   nbr = (const int*)d_in[1];
  const float* W1 = (const float*)d_in[2];
  const float* g1 = (const float*)d_in[3];
  const float* b1 = (const float*)d_in[4];
  const float* Wk = (const float*)d_in[5];
  const float* g2 = (const float*)d_in[6];
  const float* b2 = (const float*)d_in[7];
  const float* W3 = (const float*)d_in[8];
  const float* g3 = (const float*)d_in[9];
  const float* b3 = (const float*)d_in[10];
  const float* Ws = (const float*)d_in[11];
  const float* gs = (const float*)d_in[12];
  const float* bs = (const float*)d_in[13];
  float* out = (float*)d_out;
  float* ws  = (float*)d_ws;

  const int N = in_sizes[0] / 64;
  const float invN = 1.f / (float)N;
  const int ntiles = (N + 63) / 64;

  // ws layout (float offsets)
  float* sum1S = ws + 0;     // [320]
  float* sq1S  = ws + 320;   // [320]
  float* sum2  = ws + 640;   // [64]
  float* sq2   = ws + 704;   // [64]
  float* sum3  = ws + 768;   // [256]
  float* sq3   = ws + 1024;  // [256]
  ushort* WP1S = (ushort*)(ws + 1280);   // 20480 bf16
  ushort* WPkP = (ushort*)(ws + 11520);  // 36864 bf16
  ushort* WP3P = (ushort*)(ws + 29952);  // 16384 bf16
  ushort* Xb   = (ushort*)(ws + 38144);                      // N*64 bf16
  ushort* Y2b  = (ushort*)(ws + 38144 + (size_t)N * 32);     // N*64 bf16
  ushort* H1b  = (ushort*)(ws + 38144 + (size_t)N * 64);     // N*64 bf16

  const int convGrid = 512;
  const int tpb = (ntiles + convGrid - 1) / convGrid;

  kPackW<<<288, 256, 0, stream>>>(W1, Ws, Wk, W3, WP1S, WPkP, WP3P, ws);
  kStatsXW<<<508, 256, 0, stream>>>(X, WP1S, Xb, sum1S, sq1S, N, ntiles);
  kGemm1<<<ntiles, 256, 0, stream>>>(Xb, WP1S, sum1S, sq1S, g1, b1, invN, H1b, N);
  kConv<<<convGrid, 256, 0, stream>>>(H1b, nbr, WPkP, Y2b, sum2, sq2, N, ntiles, tpb);
  kH2S3<<<508, 256, 0, stream>>>(Y2b, sum2, sq2, g2, b2, invN, WP3P, sum3, sq3, N, ntiles);
  kFinal<<<ntiles, 256, 0, stream>>>(Y2b, Xb, WP3P, WP1S, sum2, sq2, g2, b2,
                                     sum3, sq3, g3, b3, sum1S + 64, sq1S + 64,
                                     gs, bs, invN, out, N);
}